// Round 13
// baseline (137.860 us; speedup 1.0000x reference)
//
#include <hip/hip_runtime.h>
#include <hip/hip_bf16.h>

// MoE: B=2,S=2048,D=512,E=8,H=1024,TOP_K=2. fp32 in/out, bf16 MFMA internally.
// 5 launches: prep -> build_lists -> gemm_up -> gemm_down -> combine.
// r13: EXACT-SIZED grids with per-block m-tile loops (zero dead blocks).
//   gemm_up:   512 blocks. h<256 routed: e=h>>5, nx=h&7, strip=(h>>3)&3;
//              loop mt=strip; mt*128<counts[e]; mt+=4  (silu -> Hbuf).
//              h>=256 shared dual-B: nx=(h-256)&15, mstrip=(h-256)>>4;
//              loop mt=mstrip; mt<32; mt+=16  (silu(gate)*up -> ACT).
//   gemm_down: 512 blocks. h<256 routed split-K=2: ek=h>>4 (e=ek>>1,kh=ek&1),
//              nx=h&3, strip=(h>>2)&3; loop mt=strip; mt+=4 (-> eo0/eo1 bf16).
//              h>=256 shared: kh=s>>7, nx=s&3, mt=(s>>2)&31 (-> sh0/sh1 fp32).
//   All strips of one (e,nx) B-panel land on one XCD (h%8 = nx, strip-stride
//   multiple of 8) -> L2 panel reuse by construction, balanced per XCD.
// GEMM core (unchanged r11): 128-row tile, BK=32, 8 waves, 3-buffer 1-barrier
// counted-vmcnt pipeline {vmcnt(2); s_barrier; sched_barrier(0); STAGE(kt+2);
// ds_read; [compiler counted lgkmcnt]; setprio(1); MFMA; setprio(0)}.
// Between m-tiles: syncthreads (drain) -> reload rowE -> syncthreads -> prologue.
// T2 pre-swizzle kept (0 bank conflicts measured).

#define NTOK 4096
#define DDIM 512
#define HDIM 1024
#define NEXP 8
#define CAP  4096

typedef unsigned short u16;
typedef __attribute__((ext_vector_type(8))) short short8;
typedef __attribute__((ext_vector_type(4))) float f32x4;

__device__ __forceinline__ u16 f2bf(float f) {
  unsigned u = __float_as_uint(f);
  u += 0x7fffu + ((u >> 16) & 1u);   // RNE
  return (u16)(u >> 16);
}
__device__ __forceinline__ float bf2f(u16 v) {
  return __uint_as_float(((unsigned)v) << 16);
}
__device__ __forceinline__ float silu_f(float v) { return v / (1.0f + __expf(-v)); }

__device__ __forceinline__ void gload16(const u16* g, u16* l) {
  __builtin_amdgcn_global_load_lds((const __attribute__((address_space(1))) void*)g,
                                   (__attribute__((address_space(3))) void*)l, 16, 0, 0);
}

// ---------------- prep: router (blocks 0..1023) + all weight cvt (rest) --------
__global__ __launch_bounds__(256) void prep(
    const float* __restrict__ x,   const float* __restrict__ gw,
    const float* __restrict__ w1,  const float* __restrict__ w2,
    const float* __restrict__ sgg, const float* __restrict__ sgu,
    const float* __restrict__ sgd,
    u16* __restrict__ Xb, u16* __restrict__ W1b, u16* __restrict__ W2b,
    u16* __restrict__ SGGb, u16* __restrict__ SGUb, u16* __restrict__ SGDb,
    int* __restrict__ tIdx, float2* __restrict__ tW) {
  if (blockIdx.x < NTOK / 4) {
    const int lane = threadIdx.x & 63;
    const int wid  = threadIdx.x >> 6;
    const int t = blockIdx.x * 4 + wid;
    const float4* xr = (const float4*)(x + (size_t)t * DDIM + lane * 8);
    const float4 x0 = xr[0], x1 = xr[1];
    short8 xbv;
    xbv[0]=f2bf(x0.x); xbv[1]=f2bf(x0.y); xbv[2]=f2bf(x0.z); xbv[3]=f2bf(x0.w);
    xbv[4]=f2bf(x1.x); xbv[5]=f2bf(x1.y); xbv[6]=f2bf(x1.z); xbv[7]=f2bf(x1.w);
    *(short8*)&Xb[(size_t)t * DDIM + lane * 8] = xbv;
    float p[NEXP];
#pragma unroll
    for (int e = 0; e < NEXP; ++e) {
      const float4* gr = (const float4*)(gw + (size_t)e * DDIM + lane * 8);
      const float4 g0 = gr[0], g1 = gr[1];
      p[e] = x0.x*g0.x + x0.y*g0.y + x0.z*g0.z + x0.w*g0.w +
             x1.x*g1.x + x1.y*g1.y + x1.z*g1.z + x1.w*g1.w;
    }
#pragma unroll
    for (int e = 0; e < NEXP; ++e) {
#pragma unroll
      for (int m = 32; m >= 1; m >>= 1) p[e] += __shfl_xor(p[e], m);
    }
    if (lane == 0) {
      int i0 = 0; float v0 = p[0];
#pragma unroll
      for (int e = 1; e < NEXP; ++e) if (p[e] > v0) { v0 = p[e]; i0 = e; }
      int i1 = -1; float v1 = -3.0e38f;
#pragma unroll
      for (int e = 0; e < NEXP; ++e) if (e != i0 && p[e] > v1) { v1 = p[e]; i1 = e; }
      const float ex1 = __expf(v1 - v0);        // v0 >= v1
      const float inv = 1.0f / (1.0f + ex1);
      tIdx[t] = i0 | (i1 << 4);
      tW[t] = make_float2(inv, ex1 * inv);
    }
  } else {
    constexpr int NW1 = NEXP * HDIM * DDIM / 4;   // float4 count
    constexpr int NSG = HDIM * DDIM / 4;
    constexpr int TOT = 2 * NW1 + 3 * NSG;
    int i = (blockIdx.x - NTOK / 4) * 256 + threadIdx.x;
    const int stride = (gridDim.x - NTOK / 4) * 256;
    for (; i < TOT; i += stride) {
      const float* s; u16* d; int j = i;
      if (j < NW1)               { s = w1;  d = W1b;  }
      else if ((j -= NW1) < NW1) { s = w2;  d = W2b;  }
      else if ((j -= NW1) < NSG) { s = sgg; d = SGGb; }
      else if ((j -= NSG) < NSG) { s = sgu; d = SGUb; }
      else        { j -= NSG;      s = sgd; d = SGDb; }
      float4 v = ((const float4*)s)[j];
      ushort4 o;
      o.x = f2bf(v.x); o.y = f2bf(v.y); o.z = f2bf(v.z); o.w = f2bf(v.w);
      ((ushort4*)d)[j] = o;
    }
  }
}

// ---------------- per-expert list build (ballot + LDS counter) ------------------
__global__ __launch_bounds__(256) void build_lists(
    const int* __restrict__ tIdx,
    int* __restrict__ counts, int* __restrict__ elist) {
  const int e = blockIdx.x;
  __shared__ int cnt;
  if (threadIdx.x == 0) cnt = 0;
  __syncthreads();
  const int lane = threadIdx.x & 63;
  int* el = elist + e * CAP;
  for (int base = 0; base < NTOK; base += 256) {
    const int t = base + threadIdx.x;
    const int pk = tIdx[t];
#pragma unroll
    for (int slot = 0; slot < 2; ++slot) {
      const bool m = (((pk >> (slot * 4)) & 15) == e);
      const unsigned long long b = __ballot(m);
      const int my  = __popcll(b & ((1ull << lane) - 1));
      const int tot = __popcll(b);
      int wbase = 0;
      if (lane == 0 && tot) wbase = atomicAdd(&cnt, tot);
      wbase = __shfl(wbase, 0);
      if (m) el[wbase + my] = t * 2 + slot;
    }
  }
  __syncthreads();
  if (threadIdx.x == 0) counts[e] = cnt;
}

// ================= shared GEMM K-loop pieces ====================================
#define BUFE (128 * 32)   // elements per LDS buffer (128 rows x 32 bf16)

// ---------------- up GEMM: K=512, 8 waves, exact grid (512 blocks) -------------
__global__ __launch_bounds__(512, 6) void gemm_up(
    const u16* __restrict__ Xb, const u16* __restrict__ W1b,
    const u16* __restrict__ SGGb, const u16* __restrict__ SGUb,
    u16* __restrict__ Hbuf, u16* __restrict__ ACT,
    const int* __restrict__ counts, const int* __restrict__ elist) {
  constexpr int KDIM = DDIM, KSTEP = KDIM / 32;
  const int h = blockIdx.x;
  const int tid = threadIdx.x;
  const int wid = tid >> 6, lane = tid & 63;
  const int row = tid >> 2;
  const int kcp = ((tid & 3) - ((row >> 1) & 3)) & 3;   // T2 pre-swizzle
  const int lr = lane & 15, lk = lane >> 4;
  const int rslot = ((lk + ((lr >> 1) & 3)) & 3) * 8;   // swizzled read slot

  __shared__ __align__(16) u16 As[3 * BUFE];
  __shared__ __align__(16) u16 Bs[3 * BUFE];
  __shared__ int rowE[128];

  const f32x4 zero = {0.f, 0.f, 0.f, 0.f};

  if (h < 256) {
    // ---- routed: e = h>>5, nx = h&7, strip = (h>>3)&3 ----
    const int e = h >> 5;
    const int nx = h & 7, strip = (h >> 3) & 3;
    const int mlim = counts[e];
    const int* lst = elist + e * CAP;
    const u16* Bp = W1b + (size_t)e * HDIM * KDIM;
    const u16* bG = Bp + (size_t)(nx * 128 + row) * KDIM + kcp * 8;
    const int n0 = nx * 128;
    const int wm = (wid >> 2) * 64, wn = (wid & 3) * 32;

    for (int mt = strip; mt * 128 < mlim; mt += 4) {
      const int m0 = mt * 128;
      __syncthreads();                    // drain prior tile (lgkm+vm at 0)
      if (tid < 128) {
        int idx = m0 + tid; if (idx > mlim - 1) idx = mlim - 1;
        rowE[tid] = lst[idx];
      }
      __syncthreads();
      const u16* aG = Xb + (size_t)(rowE[row] >> 1) * KDIM + kcp * 8;

      f32x4 acc[4][2];
#pragma unroll
      for (int i = 0; i < 4; ++i)
#pragma unroll
        for (int j = 0; j < 2; ++j) acc[i][j] = zero;

      auto STAGE = [&](int kt, int c) {
        gload16(aG + kt * 32, As + c * BUFE + tid * 8);
        gload16(bG + kt * 32, Bs + c * BUFE + tid * 8);
      };
      STAGE(0, 0); STAGE(1, 1);
      for (int kt = 0; kt < KSTEP; ++kt) {
        if (kt + 1 < KSTEP) asm volatile("s_waitcnt vmcnt(2)" ::: "memory");
        else                asm volatile("s_waitcnt vmcnt(0)" ::: "memory");
        __builtin_amdgcn_s_barrier();
        __builtin_amdgcn_sched_barrier(0);
        if (kt + 2 < KSTEP) STAGE(kt + 2, (kt + 2) % 3);
        const u16* ab = As + (kt % 3) * BUFE;
        const u16* bb = Bs + (kt % 3) * BUFE;
        short8 a[4], b[2];
#pragma unroll
        for (int i = 0; i < 4; ++i)
          a[i] = *(const short8*)&ab[(wm + i * 16 + lr) * 32 + rslot];
#pragma unroll
        for (int j = 0; j < 2; ++j)
          b[j] = *(const short8*)&bb[(wn + j * 16 + lr) * 32 + rslot];
        __builtin_amdgcn_s_setprio(1);
#pragma unroll
        for (int i = 0; i < 4; ++i)
#pragma unroll
          for (int j = 0; j < 2; ++j)
            acc[i][j] = __builtin_amdgcn_mfma_f32_16x16x32_bf16(a[i], b[j], acc[i][j], 0, 0, 0);
        __builtin_amdgcn_s_setprio(0);
      }

      // epilogue: C/D layout col=lane&15, row=(lane>>4)*4+r  [m89-verified]
#pragma unroll
      for (int i = 0; i < 4; ++i) {
#pragma unroll
        for (int j = 0; j < 2; ++j) {
          const int col = n0 + wn + j * 16 + lr;
#pragma unroll
          for (int r = 0; r < 4; ++r) {
            const int m = wm + i * 16 + lk * 4 + r;
            if (m0 + m < mlim)
              Hbuf[(size_t)rowE[m] * HDIM + col] = f2bf(silu_f(acc[i][j][r]));
          }
        }
      }
    }
  } else {
    // ---- shared dual-B: nx = (h-256)&15, mstrip = (h-256)>>4 ----
    const int s = h - 256;
    const int nx = s & 15, mstrip = s >> 4;
    const int n0 = nx * 64;
    const u16* bG = (row < 64)
        ? SGGb + (size_t)(n0 + row) * KDIM + kcp * 8
        : SGUb + (size_t)(n0 + row - 64) * KDIM + kcp * 8;
    const int wm = (wid >> 2) * 64, ws = (wid & 3) * 16;

    for (int mt = mstrip; mt < 32; mt += 16) {
      const int m0 = mt * 128;
      __syncthreads();                    // LDS buffer reuse safety across tiles
      const u16* aG = Xb + (size_t)(m0 + row) * KDIM + kcp * 8;

      f32x4 ag[4], au[4];
#pragma unroll
      for (int i = 0; i < 4; ++i) { ag[i] = zero; au[i] = zero; }

      auto STAGE = [&](int kt, int c) {
        gload16(aG + kt * 32, As + c * BUFE + tid * 8);
        gload16(bG + kt * 32, Bs + c * BUFE + tid * 8);
      };
      STAGE(0, 0); STAGE(1, 1);
      for (int kt = 0; kt < KSTEP; ++kt) {
        if (kt + 1 < KSTEP) asm volatile("s_waitcnt vmcnt(2)" ::: "memory");
        else                asm volatile("s_waitcnt vmcnt(0)" ::: "memory");
        __builtin_amdgcn_s_barrier();
        __builtin_amdgcn_sched_barrier(0);
        if (kt + 2 < KSTEP) STAGE(kt + 2, (kt + 2) % 3);
        const u16* ab = As + (kt % 3) * BUFE;
        const u16* bb = Bs + (kt % 3) * BUFE;
        short8 a[4], bg, bu;
#pragma unroll
        for (int i = 0; i < 4; ++i)
          a[i] = *(const short8*)&ab[(wm + i * 16 + lr) * 32 + rslot];
        bg = *(const short8*)&bb[(ws + lr) * 32 + rslot];        // SGG rows 0..63
        bu = *(const short8*)&bb[(64 + ws + lr) * 32 + rslot];   // SGU rows 64..127
        __builtin_amdgcn_s_setprio(1);
#pragma unroll
        for (int i = 0; i < 4; ++i) {
          ag[i] = __builtin_amdgcn_mfma_f32_16x16x32_bf16(a[i], bg, ag[i], 0, 0, 0);
          au[i] = __builtin_amdgcn_mfma_f32_16x16x32_bf16(a[i], bu, au[i], 0, 0, 0);
        }
        __builtin_amdgcn_s_setprio(0);
      }

#pragma unroll
      for (int i = 0; i < 4; ++i) {
        const int col = n0 + ws + lr;
#pragma unroll
        for (int r = 0; r < 4; ++r) {
          const int m = wm + i * 16 + lk * 4 + r;
          ACT[(size_t)(m0 + m) * HDIM + col] = f2bf(silu_f(ag[i][r]) * au[i][r]);
        }
      }
    }
  }
}

// ---------------- down GEMM: split-K=2, 8 waves, exact grid (512 blocks) -------
__global__ __launch_bounds__(512, 6) void gemm_down(
    const u16* __restrict__ Hbuf, const u16* __restrict__ W2b,
    const u16* __restrict__ ACT,  const u16* __restrict__ SGDb,
    u16* __restrict__ eo0, u16* __restrict__ eo1,
    float* __restrict__ sh0, float* __restrict__ sh1,
    const int* __restrict__ counts, const int* __restrict__ elist) {
  constexpr int KFULL = HDIM;            // row stride of A and B
  constexpr int KSTEP = 512 / 32;        // 16 steps over this half
  const int h = blockIdx.x;
  const int tid = threadIdx.x;
  const int wid = tid >> 6, lane = tid & 63;
  const int row = tid >> 2;
  const int kcp = ((tid & 3) - ((row >> 1) & 3)) & 3;
  const int lr = lane & 15, lk = lane >> 4;
  const int rslot = ((lk + ((lr >> 1) & 3)) & 3) * 8;
  const int wm = (wid >> 2) * 64, wn = (wid & 3) * 32;

  __shared__ __align__(16) u16 As[3 * BUFE];
  __shared__ __align__(16) u16 Bs[3 * BUFE];
  __shared__ int rowE[128];

  const f32x4 zero = {0.f, 0.f, 0.f, 0.f};

  if (h < 256) {
    // ---- routed: ek = h>>4 (e=ek>>1, kh=ek&1), nx = h&3, strip = (h>>2)&3 ----
    const int ek = h >> 4;
    const int e = ek >> 1, khalf = ek & 1;
    const int nx = h & 3, strip = (h >> 2) & 3;
    const int koff = khalf * 512;
    const int mlim = counts[e];
    const int* lst = elist + e * CAP;
    const u16* Bp = W2b + (size_t)e * DDIM * KFULL;
    const u16* bG = Bp + (size_t)(nx * 128 + row) * KFULL + koff + kcp * 8;
    const int n0 = nx * 128;
    u16* dst = khalf ? eo1 : eo0;

    for (int mt = strip; mt * 128 < mlim; mt += 4) {
      const int m0 = mt * 128;
      __syncthreads();
      if (tid < 128) {
        int idx = m0 + tid; if (idx > mlim - 1) idx = mlim - 1;
        rowE[tid] = lst[idx];
      }
      __syncthreads();
      const u16* aG = Hbuf + (size_t)rowE[row] * KFULL + koff + kcp * 8;

      f32x4 acc[4][2];
#pragma unroll
      for (int i = 0; i < 4; ++i)
#pragma unroll
        for (int j = 0; j < 2; ++j) acc[i][j] = zero;

      auto STAGE = [&](int kt, int c) {
        gload16(aG + kt * 32, As + c * BUFE + tid * 8);
        gload16(bG + kt * 32, Bs + c * BUFE + tid * 8);
      };
      STAGE(0, 0); STAGE(1, 1);
      for (int kt = 0; kt < KSTEP; ++kt) {
        if (kt + 1 < KSTEP) asm volatile("s_waitcnt vmcnt(2)" ::: "memory");
        else                asm volatile("s_waitcnt vmcnt(0)" ::: "memory");
        __builtin_amdgcn_s_barrier();
        __builtin_amdgcn_sched_barrier(0);
        if (kt + 2 < KSTEP) STAGE(kt + 2, (kt + 2) % 3);
        const u16* ab = As + (kt % 3) * BUFE;
        const u16* bb = Bs + (kt % 3) * BUFE;
        short8 a[4], b[2];
#pragma unroll
        for (int i = 0; i < 4; ++i)
          a[i] = *(const short8*)&ab[(wm + i * 16 + lr) * 32 + rslot];
#pragma unroll
        for (int j = 0; j < 2; ++j)
          b[j] = *(const short8*)&bb[(wn + j * 16 + lr) * 32 + rslot];
        __builtin_amdgcn_s_setprio(1);
#pragma unroll
        for (int i = 0; i < 4; ++i)
#pragma unroll
          for (int j = 0; j < 2; ++j)
            acc[i][j] = __builtin_amdgcn_mfma_f32_16x16x32_bf16(a[i], b[j], acc[i][j], 0, 0, 0);
        __builtin_amdgcn_s_setprio(0);
      }

#pragma unroll
      for (int i = 0; i < 4; ++i) {
#pragma unroll
        for (int j = 0; j < 2; ++j) {
          const int col = n0 + wn + j * 16 + lr;
#pragma unroll
          for (int r = 0; r < 4; ++r) {
            const int m = wm + i * 16 + lk * 4 + r;
            if (m0 + m < mlim)
              dst[(size_t)rowE[m] * DDIM + col] = f2bf(acc[i][j][r]);
          }
        }
      }
    }
  } else {
    // ---- shared: s = h-256; khalf = s>>7, nx = s&3, mt = (s>>2)&31 ----
    const int s = h - 256;
    const int khalf = s >> 7;
    const int nx = s & 3, mt = (s >> 2) & 31;
    const int koff = khalf * 512;
    const int n0 = nx * 128;
    const int m0 = mt * 128;
    float* dst = khalf ? sh1 : sh0;
    const u16* aG = ACT  + (size_t)(m0 + row) * KFULL + koff + kcp * 8;
    const u16* bG = SGDb + (size_t)(n0 + row) * KFULL + koff + kcp * 8;

    f32x4 acc[4][2];
#pragma unroll
    for (int i = 0; i < 4; ++i)
#pragma unroll
      for (int j = 0; j < 2; ++j) acc[i][j] = zero;

    auto STAGE = [&](int kt, int c) {
      gload16(aG + kt * 32, As + c * BUFE + tid * 8);
      gload16(bG + kt * 32, Bs + c * BUFE + tid * 8);
    };
    STAGE(0, 0); STAGE(1, 1);
    for (int kt = 0; kt < KSTEP; ++kt) {
      if (kt + 1 < KSTEP) asm volatile("s_waitcnt vmcnt(2)" ::: "memory");
      else                asm volatile("s_waitcnt vmcnt(0)" ::: "memory");
      __builtin_amdgcn_s_barrier();
      __builtin_amdgcn_sched_barrier(0);
      if (kt + 2 < KSTEP) STAGE(kt + 2, (kt + 2) % 3);
      const u16* ab = As + (kt % 3) * BUFE;
      const u16* bb = Bs + (kt % 3) * BUFE;
      short8 a[4], b[2];
#pragma unroll
      for (int i = 0; i < 4; ++i)
        a[i] = *(const short8*)&ab[(wm + i * 16 + lr) * 32 + rslot];
#pragma unroll
      for (int j = 0; j < 2; ++j)
        b[j] = *(const short8*)&bb[(wn + j * 16 + lr) * 32 + rslot];
      __builtin_amdgcn_s_setprio(1);
#pragma unroll
      for (int i = 0; i < 4; ++i)
#pragma unroll
        for (int j = 0; j < 2; ++j)
          acc[i][j] = __builtin_amdgcn_mfma_f32_16x16x32_bf16(a[i], b[j], acc[i][j], 0, 0, 0);
      __builtin_amdgcn_s_setprio(0);
    }

#pragma unroll
    for (int i = 0; i < 4; ++i) {
#pragma unroll
      for (int j = 0; j < 2; ++j) {
        const int col = n0 + wn + j * 16 + lr;
#pragma unroll
        for (int r = 0; r < 4; ++r) {
          const int m = wm + i * 16 + lk * 4 + r;
          dst[(size_t)(m0 + m) * DDIM + col] = acc[i][j][r];
        }
      }
    }
  }
}

// ------- combine: out = sh0+sh1 + w0*(eo0+eo1)[2t] + w1*(eo0+eo1)[2t+1] --------
__global__ __launch_bounds__(256) void combine_kernel(
    const u16* __restrict__ eo0, const u16* __restrict__ eo1,
    const float* __restrict__ sh0, const float* __restrict__ sh1,
    const float2* __restrict__ tW, float* __restrict__ out) {
  const int g = blockIdx.x * 256 + threadIdx.x;
  const int t = g >> 6;
  const int c0 = (g & 63) * 8;
  const float2 w = tW[t];
  const size_t r0 = (size_t)(t * 2) * DDIM + c0;
  const size_t r1 = (size_t)(t * 2 + 1) * DDIM + c0;
  const short8 a0 = *(const short8*)&eo0[r0];
  const short8 a1 = *(const short8*)&eo0[r1];
  const short8 b0 = *(const short8*)&eo1[r0];
  const short8 b1 = *(const short8*)&eo1[r1];
  const size_t so = (size_t)t * DDIM + c0;
  const float4 s0a = ((const float4*)(sh0 + so))[0];
  const float4 s0b = ((const float4*)(sh0 + so))[1];
  const float4 s1a = ((const float4*)(sh1 + so))[0];
  const float4 s1b = ((const float4*)(sh1 + so))[1];
  float o[8];
  o[0]=s0a.x+s1a.x; o[1]=s0a.y+s1a.y; o[2]=s0a.z+s1a.z; o[3]=s0a.w+s1a.w;
  o[4]=s0b.x+s1b.x; o[5]=s0b.y+s1b.y; o[6]=s0b.z+s1b.z; o[7]=s0b.w+s1b.w;
#pragma unroll
  for (int k = 0; k < 8; ++k)
    o[k] += w.x * (bf2f((u16)a0[k]) + bf2f((u16)b0[k])) +
            w.y * (bf2f((u16)a1[k]) + bf2f((u16)b1[k]));
  float4 v0 = {o[0], o[1], o[2], o[3]};
  float4 v1 = {o[4], o[5], o[6], o[7]};
  ((float4*)(out + so))[0] = v0;
  ((float4*)(out + so))[1] = v1;
}

extern "C" void kernel_launch(void* const* d_in, const int* in_sizes, int n_in,
                              void* d_out, int out_size, void* d_ws, size_t ws_size,
                              hipStream_t stream) {
  const float* x    = (const float*)d_in[0];
  const float* gw   = (const float*)d_in[1];
  const float* w1   = (const float*)d_in[2];
  const float* w2   = (const float*)d_in[3];
  const float* sgg  = (const float*)d_in[4];
  const float* sgu  = (const float*)d_in[5];
  const float* sgd  = (const float*)d_in[6];
  float* out = (float*)d_out;

  char* ws = (char*)d_ws;
  size_t off = 0;
  auto take = [&](size_t bytes) {
    size_t r = off; off += (bytes + 255) & ~(size_t)255; return r;
  };
  int*    counts = (int*)   (ws + take(NEXP * sizeof(int)));
  int*    elist  = (int*)   (ws + take((size_t)NEXP * CAP * sizeof(int)));
  int*    tIdx   = (int*)   (ws + take((size_t)NTOK * sizeof(int)));
  float2* tW     = (float2*)(ws + take((size_t)NTOK * sizeof(float2)));
  u16*    Xb     = (u16*)   (ws + take((size_t)NTOK * DDIM * 2));
  u16*    W1b    = (u16*)   (ws + take((size_t)NEXP * HDIM * DDIM * 2));
  u16*    W2b    = (u16*)   (ws + take((size_t)NEXP * DDIM * HDIM * 2));
  u16*    SGGb   = (u16*)   (ws + take((size_t)HDIM * DDIM * 2));
  u16*    SGUb   = (u16*)   (ws + take((size_t)HDIM * DDIM * 2));
  u16*    SGDb   = (u16*)   (ws + take((size_t)DDIM * HDIM * 2));
  u16*    Hbuf   = (u16*)   (ws + take((size_t)NTOK * 2 * HDIM * 2));
  u16*    ACT    = (u16*)   (ws + take((size_t)NTOK * HDIM * 2));
  u16*    eo0    = (u16*)   (ws + take((size_t)NTOK * 2 * DDIM * 2));
  u16*    eo1    = (u16*)   (ws + take((size_t)NTOK * 2 * DDIM * 2));
  float*  sh0    = (float*) (ws + take((size_t)NTOK * DDIM * 4));
  float*  sh1    = (float*) (ws + take((size_t)NTOK * DDIM * 4));
  if (off > ws_size) return;

  prep<<<dim3(3072), 256, 0, stream>>>(x, gw, w1, w2, sgg, sgu, sgd,
                                       Xb, W1b, W2b, SGGb, SGUb, SGDb, tIdx, tW);
  build_lists<<<NEXP, 256, 0, stream>>>(tIdx, counts, elist);
  gemm_up<<<dim3(512), 512, 0, stream>>>(
      Xb, W1b, SGGb, SGUb, Hbuf, ACT, counts, elist);
  gemm_down<<<dim3(512), 512, 0, stream>>>(
      Hbuf, W2b, ACT, SGDb, eo0, eo1, sh0, sh1, counts, elist);
  combine_kernel<<<NTOK * 64 / 256, 256, 0, stream>>>(eo0, eo1, sh0, sh1, tW, out);
}

// Round 14
// 111.479 us; speedup vs baseline: 1.2366x; 1.2366x over previous
//
#include <hip/hip_runtime.h>
#include <hip/hip_bf16.h>

// MoE: B=2,S=2048,D=512,E=8,H=1024,TOP_K=2. fp32 in/out, bf16 MFMA internally.
// 5 launches: prep -> build_lists
//   -> gemm_up   (z<8, nx<8: routed silu->Hbuf | z=8: shared DUAL-B 64-col
//                 tiles, silu(gate)*up -> ACT)                     [r11 exact]
//   -> gemm_down (z<16 routed split-K=2 -> eo0/eo1 bf16;
//                 z=16 shared FULL-K=1024 -> out fp32 direct)      [r14 change]
//   -> combine   (out += w0*(eo0+eo1)[2t] + w1*(eo0+eo1)[2t+1])    [RMW, slim]
// GEMM core (r11, best measured 106.4us): 128-row tile, BK=32, 8 waves,
// 3-buffer 1-barrier counted-vmcnt pipeline {vmcnt(2); s_barrier;
// sched_barrier(0); STAGE(kt+2); ds_read; [compiler counted lgkmcnt];
// setprio(1); MFMA; setprio(0)}. T2 pre-swizzle (0 bank conflicts measured).
// r14 removes the shared-down split-K round-trip: sh0/sh1 (16MB write + 16MB
// read) eliminated; shared down writes out directly (full coverage each call).
// Lessons kept: no XCD swizzle (r6/r12 null), no persistent strips (r13 regr),
// no 4-buffer depth (r8 regr), occupancy > lookahead (r9).

#define NTOK 4096
#define DDIM 512
#define HDIM 1024
#define NEXP 8
#define CAP  4096

typedef unsigned short u16;
typedef __attribute__((ext_vector_type(8))) short short8;
typedef __attribute__((ext_vector_type(4))) float f32x4;

__device__ __forceinline__ u16 f2bf(float f) {
  unsigned u = __float_as_uint(f);
  u += 0x7fffu + ((u >> 16) & 1u);   // RNE
  return (u16)(u >> 16);
}
__device__ __forceinline__ float bf2f(u16 v) {
  return __uint_as_float(((unsigned)v) << 16);
}
__device__ __forceinline__ float silu_f(float v) { return v / (1.0f + __expf(-v)); }

__device__ __forceinline__ void gload16(const u16* g, u16* l) {
  __builtin_amdgcn_global_load_lds((const __attribute__((address_space(1))) void*)g,
                                   (__attribute__((address_space(3))) void*)l, 16, 0, 0);
}

// ---------------- prep: router (blocks 0..1023) + all weight cvt (rest) --------
__global__ __launch_bounds__(256) void prep(
    const float* __restrict__ x,   const float* __restrict__ gw,
    const float* __restrict__ w1,  const float* __restrict__ w2,
    const float* __restrict__ sgg, const float* __restrict__ sgu,
    const float* __restrict__ sgd,
    u16* __restrict__ Xb, u16* __restrict__ W1b, u16* __restrict__ W2b,
    u16* __restrict__ SGGb, u16* __restrict__ SGUb, u16* __restrict__ SGDb,
    int* __restrict__ tIdx, float2* __restrict__ tW) {
  if (blockIdx.x < NTOK / 4) {
    const int lane = threadIdx.x & 63;
    const int wid  = threadIdx.x >> 6;
    const int t = blockIdx.x * 4 + wid;
    const float4* xr = (const float4*)(x + (size_t)t * DDIM + lane * 8);
    const float4 x0 = xr[0], x1 = xr[1];
    short8 xbv;
    xbv[0]=f2bf(x0.x); xbv[1]=f2bf(x0.y); xbv[2]=f2bf(x0.z); xbv[3]=f2bf(x0.w);
    xbv[4]=f2bf(x1.x); xbv[5]=f2bf(x1.y); xbv[6]=f2bf(x1.z); xbv[7]=f2bf(x1.w);
    *(short8*)&Xb[(size_t)t * DDIM + lane * 8] = xbv;
    float p[NEXP];
#pragma unroll
    for (int e = 0; e < NEXP; ++e) {
      const float4* gr = (const float4*)(gw + (size_t)e * DDIM + lane * 8);
      const float4 g0 = gr[0], g1 = gr[1];
      p[e] = x0.x*g0.x + x0.y*g0.y + x0.z*g0.z + x0.w*g0.w +
             x1.x*g1.x + x1.y*g1.y + x1.z*g1.z + x1.w*g1.w;
    }
#pragma unroll
    for (int e = 0; e < NEXP; ++e) {
#pragma unroll
      for (int m = 32; m >= 1; m >>= 1) p[e] += __shfl_xor(p[e], m);
    }
    if (lane == 0) {
      int i0 = 0; float v0 = p[0];
#pragma unroll
      for (int e = 1; e < NEXP; ++e) if (p[e] > v0) { v0 = p[e]; i0 = e; }
      int i1 = -1; float v1 = -3.0e38f;
#pragma unroll
      for (int e = 0; e < NEXP; ++e) if (e != i0 && p[e] > v1) { v1 = p[e]; i1 = e; }
      const float ex1 = __expf(v1 - v0);        // v0 >= v1
      const float inv = 1.0f / (1.0f + ex1);
      tIdx[t] = i0 | (i1 << 4);
      tW[t] = make_float2(inv, ex1 * inv);
    }
  } else {
    constexpr int NW1 = NEXP * HDIM * DDIM / 4;   // float4 count
    constexpr int NSG = HDIM * DDIM / 4;
    constexpr int TOT = 2 * NW1 + 3 * NSG;
    int i = (blockIdx.x - NTOK / 4) * 256 + threadIdx.x;
    const int stride = (gridDim.x - NTOK / 4) * 256;
    for (; i < TOT; i += stride) {
      const float* s; u16* d; int j = i;
      if (j < NW1)               { s = w1;  d = W1b;  }
      else if ((j -= NW1) < NW1) { s = w2;  d = W2b;  }
      else if ((j -= NW1) < NSG) { s = sgg; d = SGGb; }
      else if ((j -= NSG) < NSG) { s = sgu; d = SGUb; }
      else        { j -= NSG;      s = sgd; d = SGDb; }
      float4 v = ((const float4*)s)[j];
      ushort4 o;
      o.x = f2bf(v.x); o.y = f2bf(v.y); o.z = f2bf(v.z); o.w = f2bf(v.w);
      ((ushort4*)d)[j] = o;
    }
  }
}

// ---------------- per-expert list build (ballot + LDS counter) ------------------
__global__ __launch_bounds__(256) void build_lists(
    const int* __restrict__ tIdx,
    int* __restrict__ counts, int* __restrict__ elist) {
  const int e = blockIdx.x;
  __shared__ int cnt;
  if (threadIdx.x == 0) cnt = 0;
  __syncthreads();
  const int lane = threadIdx.x & 63;
  int* el = elist + e * CAP;
  for (int base = 0; base < NTOK; base += 256) {
    const int t = base + threadIdx.x;
    const int pk = tIdx[t];
#pragma unroll
    for (int slot = 0; slot < 2; ++slot) {
      const bool m = (((pk >> (slot * 4)) & 15) == e);
      const unsigned long long b = __ballot(m);
      const int my  = __popcll(b & ((1ull << lane) - 1));
      const int tot = __popcll(b);
      int wbase = 0;
      if (lane == 0 && tot) wbase = atomicAdd(&cnt, tot);
      wbase = __shfl(wbase, 0);
      if (m) el[wbase + my] = t * 2 + slot;
    }
  }
  __syncthreads();
  if (threadIdx.x == 0) counts[e] = cnt;
}

// ================= shared GEMM K-loop pieces ====================================
#define BUFE (128 * 32)   // elements per LDS buffer (128 rows x 32 bf16)

// ---------------- up GEMM: K=512, 8 waves (r11 exact) ---------------------------
// z<8 (nx<8):  routed expert z, 128x128 tile, silu -> Hbuf[entry]
// z=8 (nx<16): shared dual-B, 128 rows x 64 cols; Bs = [SGG 64 | SGU 64];
//              epilogue: ACT = silu(gate)*up (fp32 accs).
__global__ __launch_bounds__(512, 6) void gemm_up(
    const u16* __restrict__ Xb, const u16* __restrict__ W1b,
    const u16* __restrict__ SGGb, const u16* __restrict__ SGUb,
    u16* __restrict__ Hbuf, u16* __restrict__ ACT,
    const int* __restrict__ counts, const int* __restrict__ elist) {
  constexpr int KDIM = DDIM, KSTEP = KDIM / 32;
  const int z = blockIdx.z;
  const int m0 = blockIdx.y * 128;
  const bool routed = (z < NEXP);

  int mlim; const u16* Bp = nullptr; const int* lst = nullptr;
  if (routed) {
    if (blockIdx.x >= 8) return;         // routed uses 8 x-tiles of 128
    mlim = counts[z];
    lst = elist + z * CAP;
    Bp = W1b + (size_t)z * HDIM * KDIM;
  } else {
    mlim = NTOK;
  }
  if (m0 >= mlim) return;

  __shared__ __align__(16) u16 As[3 * BUFE];
  __shared__ __align__(16) u16 Bs[3 * BUFE];
  __shared__ int rowE[128];

  const int tid = threadIdx.x;
  const int wid = tid >> 6, lane = tid & 63;

  if (routed) {
    if (tid < 128) {
      int idx = m0 + tid; if (idx > mlim - 1) idx = mlim - 1;
      rowE[tid] = lst[idx];
    }
    __syncthreads();
  }

  // staging: one slot/thread. row=tid>>2, slotpos=tid&3; LDS dest linear;
  // global chunk pre-swizzled kc' = (slotpos - ((row>>1)&3))&3.
  const int row = tid >> 2;
  const int kcp = ((tid & 3) - ((row >> 1) & 3)) & 3;
  const int arow = routed ? (rowE[row] >> 1) : (m0 + row);
  const u16* aG = Xb + (size_t)arow * KDIM + kcp * 8;
  const u16* bG;
  if (routed) {
    bG = Bp + (size_t)(blockIdx.x * 128 + row) * KDIM + kcp * 8;
  } else {
    const int n0 = blockIdx.x * 64;
    bG = (row < 64) ? SGGb + (size_t)(n0 + row) * KDIM + kcp * 8
                    : SGUb + (size_t)(n0 + row - 64) * KDIM + kcp * 8;
  }

  const int lr = lane & 15, lk = lane >> 4;
  const int rslot = ((lk + ((lr >> 1) & 3)) & 3) * 8;   // swizzled read slot

  auto STAGE = [&](int kt, int c) {
    gload16(aG + kt * 32, As + c * BUFE + tid * 8);
    gload16(bG + kt * 32, Bs + c * BUFE + tid * 8);
  };

  const f32x4 zero = {0.f, 0.f, 0.f, 0.f};

  if (routed) {
    // ---- routed: wave tile 64x32, acc[4][2] ----
    const int n0 = blockIdx.x * 128;
    const int wm = (wid >> 2) * 64, wn = (wid & 3) * 32;
    f32x4 acc[4][2];
#pragma unroll
    for (int i = 0; i < 4; ++i)
#pragma unroll
      for (int j = 0; j < 2; ++j) acc[i][j] = zero;

    STAGE(0, 0); STAGE(1, 1);
    for (int kt = 0; kt < KSTEP; ++kt) {
      if (kt + 1 < KSTEP) asm volatile("s_waitcnt vmcnt(2)" ::: "memory");
      else                asm volatile("s_waitcnt vmcnt(0)" ::: "memory");
      __builtin_amdgcn_s_barrier();
      __builtin_amdgcn_sched_barrier(0);  // no read may hoist above the barrier
      if (kt + 2 < KSTEP) STAGE(kt + 2, (kt + 2) % 3);
      const u16* ab = As + (kt % 3) * BUFE;
      const u16* bb = Bs + (kt % 3) * BUFE;
      short8 a[4], b[2];
#pragma unroll
      for (int i = 0; i < 4; ++i)
        a[i] = *(const short8*)&ab[(wm + i * 16 + lr) * 32 + rslot];
#pragma unroll
      for (int j = 0; j < 2; ++j)
        b[j] = *(const short8*)&bb[(wn + j * 16 + lr) * 32 + rslot];
      // no forced lgkmcnt(0): compiler emits counted waits, MFMA overlaps reads
      __builtin_amdgcn_s_setprio(1);
#pragma unroll
      for (int i = 0; i < 4; ++i)
#pragma unroll
        for (int j = 0; j < 2; ++j)
          acc[i][j] = __builtin_amdgcn_mfma_f32_16x16x32_bf16(a[i], b[j], acc[i][j], 0, 0, 0);
      __builtin_amdgcn_s_setprio(0);
    }

    // epilogue: C/D layout col=lane&15, row=(lane>>4)*4+r  [m89-verified]
#pragma unroll
    for (int i = 0; i < 4; ++i) {
#pragma unroll
      for (int j = 0; j < 2; ++j) {
        const int col = n0 + wn + j * 16 + lr;
#pragma unroll
        for (int r = 0; r < 4; ++r) {
          const int m = wm + i * 16 + lk * 4 + r;
          if (m0 + m < mlim)
            Hbuf[(size_t)rowE[m] * HDIM + col] = f2bf(silu_f(acc[i][j][r]));
        }
      }
    }
  } else {
    // ---- shared dual-B: wave tile 64x16 (gate) + 64x16 (up) ----
    const int n0 = blockIdx.x * 64;
    const int wm = (wid >> 2) * 64, ws = (wid & 3) * 16;
    f32x4 ag[4], au[4];
#pragma unroll
    for (int i = 0; i < 4; ++i) { ag[i] = zero; au[i] = zero; }

    STAGE(0, 0); STAGE(1, 1);
    for (int kt = 0; kt < KSTEP; ++kt) {
      if (kt + 1 < KSTEP) asm volatile("s_waitcnt vmcnt(2)" ::: "memory");
      else                asm volatile("s_waitcnt vmcnt(0)" ::: "memory");
      __builtin_amdgcn_s_barrier();
      __builtin_amdgcn_sched_barrier(0);
      if (kt + 2 < KSTEP) STAGE(kt + 2, (kt + 2) % 3);
      const u16* ab = As + (kt % 3) * BUFE;
      const u16* bb = Bs + (kt % 3) * BUFE;
      short8 a[4], bg, bu;
#pragma unroll
      for (int i = 0; i < 4; ++i)
        a[i] = *(const short8*)&ab[(wm + i * 16 + lr) * 32 + rslot];
      bg = *(const short8*)&bb[(ws + lr) * 32 + rslot];        // SGG rows 0..63
      bu = *(const short8*)&bb[(64 + ws + lr) * 32 + rslot];   // SGU rows 64..127
      __builtin_amdgcn_s_setprio(1);
#pragma unroll
      for (int i = 0; i < 4; ++i) {
        ag[i] = __builtin_amdgcn_mfma_f32_16x16x32_bf16(a[i], bg, ag[i], 0, 0, 0);
        au[i] = __builtin_amdgcn_mfma_f32_16x16x32_bf16(a[i], bu, au[i], 0, 0, 0);
      }
      __builtin_amdgcn_s_setprio(0);
    }

#pragma unroll
    for (int i = 0; i < 4; ++i) {
      const int col = n0 + ws + lr;
#pragma unroll
      for (int r = 0; r < 4; ++r) {
        const int m = wm + i * 16 + lk * 4 + r;
        ACT[(size_t)(m0 + m) * HDIM + col] = f2bf(silu_f(ag[i][r]) * au[i][r]);
      }
    }
  }
}

// ---------------- down GEMM: 8 waves --------------------------------------------
// z<16: routed split-K=2, e=z>>1, khalf=z&1 -> (eo0|eo1)[entry] bf16, 16 steps
// z=16: shared FULL-K=1024 -> out fp32 direct (full coverage), 32 steps
__global__ __launch_bounds__(512, 6) void gemm_down(
    const u16* __restrict__ Hbuf, const u16* __restrict__ W2b,
    const u16* __restrict__ ACT,  const u16* __restrict__ SGDb,
    u16* __restrict__ eo0, u16* __restrict__ eo1,
    float* __restrict__ out,
    const int* __restrict__ counts, const int* __restrict__ elist) {
  constexpr int KFULL = HDIM;            // row stride of A and B
  const int z = blockIdx.z;
  const int n0 = blockIdx.x * 128;
  const int m0 = blockIdx.y * 128;
  const bool routed = (z < 2 * NEXP);
  const int khalf = routed ? (z & 1) : 0;
  const int koff = khalf * 512;
  const int ksteps = routed ? 16 : 32;   // split-K half vs full K

  int mlim; const u16* Ap; const u16* Bp; const int* lst = nullptr;
  if (routed) {
    const int e = z >> 1;
    mlim = counts[e];
    lst = elist + e * CAP;
    Ap = Hbuf;
    Bp = W2b + (size_t)e * DDIM * KFULL;
  } else {
    mlim = NTOK;
    Ap = ACT;
    Bp = SGDb;
  }
  if (m0 >= mlim) return;

  __shared__ __align__(16) u16 As[3 * BUFE];
  __shared__ __align__(16) u16 Bs[3 * BUFE];
  __shared__ int rowE[128];

  const int tid = threadIdx.x;
  const int wid = tid >> 6, lane = tid & 63;

  if (routed) {
    if (tid < 128) {
      int idx = m0 + tid; if (idx > mlim - 1) idx = mlim - 1;
      rowE[tid] = lst[idx];
    }
    __syncthreads();
  }

  const int row = tid >> 2;
  const int kcp = ((tid & 3) - ((row >> 1) & 3)) & 3;
  const int arow = routed ? rowE[row] : (m0 + row);
  const u16* aG = Ap + (size_t)arow * KFULL + koff + kcp * 8;
  const u16* bG = Bp + (size_t)(n0 + row) * KFULL + koff + kcp * 8;

  const int wm = (wid >> 2) * 64, wn = (wid & 3) * 32;
  const int lr = lane & 15, lk = lane >> 4;
  const int rslot = ((lk + ((lr >> 1) & 3)) & 3) * 8;

  const f32x4 zero = {0.f, 0.f, 0.f, 0.f};
  f32x4 acc[4][2];
#pragma unroll
  for (int i = 0; i < 4; ++i)
#pragma unroll
    for (int j = 0; j < 2; ++j) acc[i][j] = zero;

  auto STAGE = [&](int kt, int c) {
    gload16(aG + kt * 32, As + c * BUFE + tid * 8);
    gload16(bG + kt * 32, Bs + c * BUFE + tid * 8);
  };

  STAGE(0, 0); STAGE(1, 1);
  for (int kt = 0; kt < ksteps; ++kt) {
    if (kt + 1 < ksteps) asm volatile("s_waitcnt vmcnt(2)" ::: "memory");
    else                 asm volatile("s_waitcnt vmcnt(0)" ::: "memory");
    __builtin_amdgcn_s_barrier();
    __builtin_amdgcn_sched_barrier(0);
    if (kt + 2 < ksteps) STAGE(kt + 2, (kt + 2) % 3);
    const u16* ab = As + (kt % 3) * BUFE;
    const u16* bb = Bs + (kt % 3) * BUFE;
    short8 a[4], b[2];
#pragma unroll
    for (int i = 0; i < 4; ++i)
      a[i] = *(const short8*)&ab[(wm + i * 16 + lr) * 32 + rslot];
#pragma unroll
    for (int j = 0; j < 2; ++j)
      b[j] = *(const short8*)&bb[(wn + j * 16 + lr) * 32 + rslot];
    __builtin_amdgcn_s_setprio(1);
#pragma unroll
    for (int i = 0; i < 4; ++i)
#pragma unroll
      for (int j = 0; j < 2; ++j)
        acc[i][j] = __builtin_amdgcn_mfma_f32_16x16x32_bf16(a[i], b[j], acc[i][j], 0, 0, 0);
    __builtin_amdgcn_s_setprio(0);
  }

#pragma unroll
  for (int i = 0; i < 4; ++i) {
#pragma unroll
    for (int j = 0; j < 2; ++j) {
      const int col = n0 + wn + j * 16 + lr;
#pragma unroll
      for (int r = 0; r < 4; ++r) {
        const int m = wm + i * 16 + lk * 4 + r;
        if (routed) {
          if (m0 + m < mlim) {
            u16* dst = khalf ? eo1 : eo0;
            dst[(size_t)rowE[m] * DDIM + col] = f2bf(acc[i][j][r]);
          }
        } else {
          out[(size_t)(m0 + m) * DDIM + col] = acc[i][j][r];  // full overwrite
        }
      }
    }
  }
}

// ------- combine: out += w0*(eo0+eo1)[2t] + w1*(eo0+eo1)[2t+1] ------------------
__global__ __launch_bounds__(256) void combine_kernel(
    const u16* __restrict__ eo0, const u16* __restrict__ eo1,
    const float2* __restrict__ tW, float* __restrict__ out) {
  const int g = blockIdx.x * 256 + threadIdx.x;
  const int t = g >> 6;
  const int c0 = (g & 63) * 8;
  const float2 w = tW[t];
  const size_t r0 = (size_t)(t * 2) * DDIM + c0;
  const size_t r1 = (size_t)(t * 2 + 1) * DDIM + c0;
  const short8 a0 = *(const short8*)&eo0[r0];
  const short8 a1 = *(const short8*)&eo0[r1];
  const short8 b0 = *(const short8*)&eo1[r0];
  const short8 b1 = *(const short8*)&eo1[r1];
  const size_t so = (size_t)t * DDIM + c0;
  float4 o0 = ((const float4*)(out + so))[0];
  float4 o1 = ((const float4*)(out + so))[1];
  float o[8] = {o0.x, o0.y, o0.z, o0.w, o1.x, o1.y, o1.z, o1.w};
#pragma unroll
  for (int k = 0; k < 8; ++k)
    o[k] += w.x * (bf2f((u16)a0[k]) + bf2f((u16)b0[k])) +
            w.y * (bf2f((u16)a1[k]) + bf2f((u16)b1[k]));
  float4 v0 = {o[0], o[1], o[2], o[3]};
  float4 v1 = {o[4], o[5], o[6], o[7]};
  ((float4*)(out + so))[0] = v0;
  ((float4*)(out + so))[1] = v1;
}

extern "C" void kernel_launch(void* const* d_in, const int* in_sizes, int n_in,
                              void* d_out, int out_size, void* d_ws, size_t ws_size,
                              hipStream_t stream) {
  const float* x    = (const float*)d_in[0];
  const float* gw   = (const float*)d_in[1];
  const float* w1   = (const float*)d_in[2];
  const float* w2   = (const float*)d_in[3];
  const float* sgg  = (const float*)d_in[4];
  const float* sgu  = (const float*)d_in[5];
  const float* sgd  = (const float*)d_in[6];
  float* out = (float*)d_out;

  char* ws = (char*)d_ws;
  size_t off = 0;
  auto take = [&](size_t bytes) {
    size_t r = off; off += (bytes + 255) & ~(size_t)255; return r;
  };
  int*    counts = (int*)   (ws + take(NEXP * sizeof(int)));
  int*    elist  = (int*)   (ws + take((size_t)NEXP * CAP * sizeof(int)));
  int*    tIdx   = (int*)   (ws + take((size_t)NTOK * sizeof(int)));
  float2* tW     = (float2*)(ws + take((size_t)NTOK * sizeof(float2)));
  u16*    Xb     = (u16*)   (ws + take((size_t)NTOK * DDIM * 2));
  u16*    W1b    = (u16*)   (ws + take((size_t)NEXP * HDIM * DDIM * 2));
  u16*    W2b    = (u16*)   (ws + take((size_t)NEXP * DDIM * HDIM * 2));
  u16*    SGGb   = (u16*)   (ws + take((size_t)HDIM * DDIM * 2));
  u16*    SGUb   = (u16*)   (ws + take((size_t)HDIM * DDIM * 2));
  u16*    SGDb   = (u16*)   (ws + take((size_t)DDIM * HDIM * 2));
  u16*    Hbuf   = (u16*)   (ws + take((size_t)NTOK * 2 * HDIM * 2));
  u16*    ACT    = (u16*)   (ws + take((size_t)NTOK * HDIM * 2));
  u16*    eo0    = (u16*)   (ws + take((size_t)NTOK * 2 * DDIM * 2));
  u16*    eo1    = (u16*)   (ws + take((size_t)NTOK * 2 * DDIM * 2));
  if (off > ws_size) return;

  prep<<<dim3(3072), 256, 0, stream>>>(x, gw, w1, w2, sgg, sgu, sgd,
                                       Xb, W1b, W2b, SGGb, SGUb, SGDb, tIdx, tW);
  build_lists<<<NEXP, 256, 0, stream>>>(tIdx, counts, elist);
  // z<8: routed (nx<8 of 128 cols); z=8: shared dual-B (nx<16 of 64 cols)
  gemm_up<<<dim3(16, 32, NEXP + 1), 512, 0, stream>>>(
      Xb, W1b, SGGb, SGUb, Hbuf, ACT, counts, elist);
  // z<16: routed split-K; z=16: shared full-K -> out
  gemm_down<<<dim3(DDIM / 128, 32, 2 * NEXP + 1), 512, 0, stream>>>(
      Hbuf, W2b, ACT, SGDb, eo0, eo1, out, counts, elist);
  combine_kernel<<<NTOK * 64 / 256, 256, 0, stream>>>(eo0, eo1, tW, out);
}

// Round 15
// 105.959 us; speedup vs baseline: 1.3011x; 1.0521x over previous
//
#include <hip/hip_runtime.h>
#include <hip/hip_bf16.h>

// MoE: B=2,S=2048,D=512,E=8,H=1024,TOP_K=2. fp32 in/out, bf16 MFMA internally.
// == r11 configuration (best measured: 106.4us) ==
// 5 launches: prep -> build_lists
//   -> gemm_up   (z<8, x<8: routed silu->Hbuf | z=8, x<16: shared DUAL-B
//                 64-col tiles, silu(gate)*up -> ACT directly)
//   -> gemm_down (split-K=2: z<16 routed -> eo0/eo1 bf16; z=16/17 shared
//                 -> sh0/sh1 fp32; all blocks uniform 16 K-steps)
//   -> combine   (out = sh0+sh1 + w0*(eo0+eo1)[2t] + w1*(eo0+eo1)[2t+1]).
// GEMM core: 128-row tile, BK=32, 8 waves (512 thr), 3-buffer 1-barrier
// counted-vmcnt pipeline {vmcnt(2); s_barrier; sched_barrier(0); STAGE(kt+2);
// ds_read; [compiler counted lgkmcnt]; setprio(1); MFMA; setprio(0)}.
// Lessons encoded: occupancy > lookahead depth (r8/r9); no forced lgkmcnt(0)
// drain (r11); uniform block duration beats traffic cuts (r14); XCD swizzles
// null-to-negative here (r6/r12); persistent strips regress (r13).
// T2 pre-swizzle kept (free; 0 bank conflicts measured).

#define NTOK 4096
#define DDIM 512
#define HDIM 1024
#define NEXP 8
#define CAP  4096

typedef unsigned short u16;
typedef __attribute__((ext_vector_type(8))) short short8;
typedef __attribute__((ext_vector_type(4))) float f32x4;

__device__ __forceinline__ u16 f2bf(float f) {
  unsigned u = __float_as_uint(f);
  u += 0x7fffu + ((u >> 16) & 1u);   // RNE
  return (u16)(u >> 16);
}
__device__ __forceinline__ float bf2f(u16 v) {
  return __uint_as_float(((unsigned)v) << 16);
}
__device__ __forceinline__ float silu_f(float v) { return v / (1.0f + __expf(-v)); }

__device__ __forceinline__ void gload16(const u16* g, u16* l) {
  __builtin_amdgcn_global_load_lds((const __attribute__((address_space(1))) void*)g,
                                   (__attribute__((address_space(3))) void*)l, 16, 0, 0);
}

// ---------------- prep: router (blocks 0..1023) + all weight cvt (rest) --------
__global__ __launch_bounds__(256) void prep(
    const float* __restrict__ x,   const float* __restrict__ gw,
    const float* __restrict__ w1,  const float* __restrict__ w2,
    const float* __restrict__ sgg, const float* __restrict__ sgu,
    const float* __restrict__ sgd,
    u16* __restrict__ Xb, u16* __restrict__ W1b, u16* __restrict__ W2b,
    u16* __restrict__ SGGb, u16* __restrict__ SGUb, u16* __restrict__ SGDb,
    int* __restrict__ tIdx, float2* __restrict__ tW) {
  if (blockIdx.x < NTOK / 4) {
    const int lane = threadIdx.x & 63;
    const int wid  = threadIdx.x >> 6;
    const int t = blockIdx.x * 4 + wid;
    const float4* xr = (const float4*)(x + (size_t)t * DDIM + lane * 8);
    const float4 x0 = xr[0], x1 = xr[1];
    short8 xbv;
    xbv[0]=f2bf(x0.x); xbv[1]=f2bf(x0.y); xbv[2]=f2bf(x0.z); xbv[3]=f2bf(x0.w);
    xbv[4]=f2bf(x1.x); xbv[5]=f2bf(x1.y); xbv[6]=f2bf(x1.z); xbv[7]=f2bf(x1.w);
    *(short8*)&Xb[(size_t)t * DDIM + lane * 8] = xbv;
    float p[NEXP];
#pragma unroll
    for (int e = 0; e < NEXP; ++e) {
      const float4* gr = (const float4*)(gw + (size_t)e * DDIM + lane * 8);
      const float4 g0 = gr[0], g1 = gr[1];
      p[e] = x0.x*g0.x + x0.y*g0.y + x0.z*g0.z + x0.w*g0.w +
             x1.x*g1.x + x1.y*g1.y + x1.z*g1.z + x1.w*g1.w;
    }
#pragma unroll
    for (int e = 0; e < NEXP; ++e) {
#pragma unroll
      for (int m = 32; m >= 1; m >>= 1) p[e] += __shfl_xor(p[e], m);
    }
    if (lane == 0) {
      int i0 = 0; float v0 = p[0];
#pragma unroll
      for (int e = 1; e < NEXP; ++e) if (p[e] > v0) { v0 = p[e]; i0 = e; }
      int i1 = -1; float v1 = -3.0e38f;
#pragma unroll
      for (int e = 0; e < NEXP; ++e) if (e != i0 && p[e] > v1) { v1 = p[e]; i1 = e; }
      const float ex1 = __expf(v1 - v0);        // v0 >= v1
      const float inv = 1.0f / (1.0f + ex1);
      tIdx[t] = i0 | (i1 << 4);
      tW[t] = make_float2(inv, ex1 * inv);
    }
  } else {
    constexpr int NW1 = NEXP * HDIM * DDIM / 4;   // float4 count
    constexpr int NSG = HDIM * DDIM / 4;
    constexpr int TOT = 2 * NW1 + 3 * NSG;
    int i = (blockIdx.x - NTOK / 4) * 256 + threadIdx.x;
    const int stride = (gridDim.x - NTOK / 4) * 256;
    for (; i < TOT; i += stride) {
      const float* s; u16* d; int j = i;
      if (j < NW1)               { s = w1;  d = W1b;  }
      else if ((j -= NW1) < NW1) { s = w2;  d = W2b;  }
      else if ((j -= NW1) < NSG) { s = sgg; d = SGGb; }
      else if ((j -= NSG) < NSG) { s = sgu; d = SGUb; }
      else        { j -= NSG;      s = sgd; d = SGDb; }
      float4 v = ((const float4*)s)[j];
      ushort4 o;
      o.x = f2bf(v.x); o.y = f2bf(v.y); o.z = f2bf(v.z); o.w = f2bf(v.w);
      ((ushort4*)d)[j] = o;
    }
  }
}

// ---------------- per-expert list build (ballot + LDS counter) ------------------
__global__ __launch_bounds__(256) void build_lists(
    const int* __restrict__ tIdx,
    int* __restrict__ counts, int* __restrict__ elist) {
  const int e = blockIdx.x;
  __shared__ int cnt;
  if (threadIdx.x == 0) cnt = 0;
  __syncthreads();
  const int lane = threadIdx.x & 63;
  int* el = elist + e * CAP;
  for (int base = 0; base < NTOK; base += 256) {
    const int t = base + threadIdx.x;
    const int pk = tIdx[t];
#pragma unroll
    for (int slot = 0; slot < 2; ++slot) {
      const bool m = (((pk >> (slot * 4)) & 15) == e);
      const unsigned long long b = __ballot(m);
      const int my  = __popcll(b & ((1ull << lane) - 1));
      const int tot = __popcll(b);
      int wbase = 0;
      if (lane == 0 && tot) wbase = atomicAdd(&cnt, tot);
      wbase = __shfl(wbase, 0);
      if (m) el[wbase + my] = t * 2 + slot;
    }
  }
  __syncthreads();
  if (threadIdx.x == 0) counts[e] = cnt;
}

// ================= shared GEMM K-loop pieces ====================================
#define BUFE (128 * 32)   // elements per LDS buffer (128 rows x 32 bf16)

// ---------------- up GEMM: K=512, 8 waves ---------------------------------------
// z<8 (x<8):  routed expert z, 128x128 tile, silu -> Hbuf[entry]
// z=8 (x<16): shared dual-B, 128 rows x 64 cols; Bs = [SGG 64 | SGU 64];
//             epilogue: ACT = silu(gate)*up (fp32 accs).
__global__ __launch_bounds__(512, 6) void gemm_up(
    const u16* __restrict__ Xb, const u16* __restrict__ W1b,
    const u16* __restrict__ SGGb, const u16* __restrict__ SGUb,
    u16* __restrict__ Hbuf, u16* __restrict__ ACT,
    const int* __restrict__ counts, const int* __restrict__ elist) {
  constexpr int KDIM = DDIM, KSTEP = KDIM / 32;
  const int z = blockIdx.z;
  const int m0 = blockIdx.y * 128;
  const bool routed = (z < NEXP);

  int mlim; const u16* Bp = nullptr; const int* lst = nullptr;
  if (routed) {
    if (blockIdx.x >= 8) return;         // routed uses 8 x-tiles of 128
    mlim = counts[z];
    lst = elist + z * CAP;
    Bp = W1b + (size_t)z * HDIM * KDIM;
  } else {
    mlim = NTOK;
  }
  if (m0 >= mlim) return;

  __shared__ __align__(16) u16 As[3 * BUFE];
  __shared__ __align__(16) u16 Bs[3 * BUFE];
  __shared__ int rowE[128];

  const int tid = threadIdx.x;
  const int wid = tid >> 6, lane = tid & 63;

  if (routed) {
    if (tid < 128) {
      int idx = m0 + tid; if (idx > mlim - 1) idx = mlim - 1;
      rowE[tid] = lst[idx];
    }
    __syncthreads();
  }

  // staging: one slot/thread. row=tid>>2, slotpos=tid&3; LDS dest linear;
  // global chunk pre-swizzled kc' = (slotpos - ((row>>1)&3))&3.
  const int row = tid >> 2;
  const int kcp = ((tid & 3) - ((row >> 1) & 3)) & 3;
  const int arow = routed ? (rowE[row] >> 1) : (m0 + row);
  const u16* aG = Xb + (size_t)arow * KDIM + kcp * 8;
  const u16* bG;
  if (routed) {
    bG = Bp + (size_t)(blockIdx.x * 128 + row) * KDIM + kcp * 8;
  } else {
    const int n0 = blockIdx.x * 64;
    bG = (row < 64) ? SGGb + (size_t)(n0 + row) * KDIM + kcp * 8
                    : SGUb + (size_t)(n0 + row - 64) * KDIM + kcp * 8;
  }

  const int lr = lane & 15, lk = lane >> 4;
  const int rslot = ((lk + ((lr >> 1) & 3)) & 3) * 8;   // swizzled read slot

  auto STAGE = [&](int kt, int c) {
    gload16(aG + kt * 32, As + c * BUFE + tid * 8);
    gload16(bG + kt * 32, Bs + c * BUFE + tid * 8);
  };

  const f32x4 zero = {0.f, 0.f, 0.f, 0.f};

  if (routed) {
    // ---- routed: wave tile 64x32, acc[4][2] ----
    const int n0 = blockIdx.x * 128;
    const int wm = (wid >> 2) * 64, wn = (wid & 3) * 32;
    f32x4 acc[4][2];
#pragma unroll
    for (int i = 0; i < 4; ++i)
#pragma unroll
      for (int j = 0; j < 2; ++j) acc[i][j] = zero;

    STAGE(0, 0); STAGE(1, 1);
    for (int kt = 0; kt < KSTEP; ++kt) {
      if (kt + 1 < KSTEP) asm volatile("s_waitcnt vmcnt(2)" ::: "memory");
      else                asm volatile("s_waitcnt vmcnt(0)" ::: "memory");
      __builtin_amdgcn_s_barrier();
      __builtin_amdgcn_sched_barrier(0);  // no read may hoist above the barrier
      if (kt + 2 < KSTEP) STAGE(kt + 2, (kt + 2) % 3);
      const u16* ab = As + (kt % 3) * BUFE;
      const u16* bb = Bs + (kt % 3) * BUFE;
      short8 a[4], b[2];
#pragma unroll
      for (int i = 0; i < 4; ++i)
        a[i] = *(const short8*)&ab[(wm + i * 16 + lr) * 32 + rslot];
#pragma unroll
      for (int j = 0; j < 2; ++j)
        b[j] = *(const short8*)&bb[(wn + j * 16 + lr) * 32 + rslot];
      // no forced lgkmcnt(0): compiler emits counted waits, MFMA overlaps reads
      __builtin_amdgcn_s_setprio(1);
#pragma unroll
      for (int i = 0; i < 4; ++i)
#pragma unroll
        for (int j = 0; j < 2; ++j)
          acc[i][j] = __builtin_amdgcn_mfma_f32_16x16x32_bf16(a[i], b[j], acc[i][j], 0, 0, 0);
      __builtin_amdgcn_s_setprio(0);
    }

    // epilogue: C/D layout col=lane&15, row=(lane>>4)*4+r  [m89-verified]
#pragma unroll
    for (int i = 0; i < 4; ++i) {
#pragma unroll
      for (int j = 0; j < 2; ++j) {
        const int col = n0 + wn + j * 16 + lr;
#pragma unroll
        for (int r = 0; r < 4; ++r) {
          const int m = wm + i * 16 + lk * 4 + r;
          if (m0 + m < mlim)
            Hbuf[(size_t)rowE[m] * HDIM + col] = f2bf(silu_f(acc[i][j][r]));
        }
      }
    }
  } else {
    // ---- shared dual-B: wave tile 64x16 (gate) + 64x16 (up) ----
    const int n0 = blockIdx.x * 64;
    const int wm = (wid >> 2) * 64, ws = (wid & 3) * 16;
    f32x4 ag[4], au[4];
#pragma unroll
    for (int i = 0; i < 4; ++i) { ag[i] = zero; au[i] = zero; }

    STAGE(0, 0); STAGE(1, 1);
    for (int kt = 0; kt < KSTEP; ++kt) {
      if (kt + 1 < KSTEP) asm volatile("s_waitcnt vmcnt(2)" ::: "memory");
      else                asm volatile("s_waitcnt vmcnt(0)" ::: "memory");
      __builtin_amdgcn_s_barrier();
      __builtin_amdgcn_sched_barrier(0);
      if (kt + 2 < KSTEP) STAGE(kt + 2, (kt + 2) % 3);
      const u16* ab = As + (kt % 3) * BUFE;
      const u16* bb = Bs + (kt % 3) * BUFE;
      short8 a[4], bg, bu;
#pragma unroll
      for (int i = 0; i < 4; ++i)
        a[i] = *(const short8*)&ab[(wm + i * 16 + lr) * 32 + rslot];
      bg = *(const short8*)&bb[(ws + lr) * 32 + rslot];        // SGG rows 0..63
      bu = *(const short8*)&bb[(64 + ws + lr) * 32 + rslot];   // SGU rows 64..127
      __builtin_amdgcn_s_setprio(1);
#pragma unroll
      for (int i = 0; i < 4; ++i) {
        ag[i] = __builtin_amdgcn_mfma_f32_16x16x32_bf16(a[i], bg, ag[i], 0, 0, 0);
        au[i] = __builtin_amdgcn_mfma_f32_16x16x32_bf16(a[i], bu, au[i], 0, 0, 0);
      }
      __builtin_amdgcn_s_setprio(0);
    }

#pragma unroll
    for (int i = 0; i < 4; ++i) {
      const int col = n0 + ws + lr;
#pragma unroll
      for (int r = 0; r < 4; ++r) {
        const int m = wm + i * 16 + lk * 4 + r;
        ACT[(size_t)(m0 + m) * HDIM + col] = f2bf(silu_f(ag[i][r]) * au[i][r]);
      }
    }
  }
}

// ---------------- down GEMM: split-K=2, 512 per half, N=512, 8 waves -----------
// z<16: routed, e=z>>1, khalf=z&1 -> (eo0|eo1)[entry] bf16
// z=16/17: shared khalf -> (sh0|sh1) fp32   (uniform 16 K-steps, no tail)
__global__ __launch_bounds__(512, 6) void gemm_down(
    const u16* __restrict__ Hbuf, const u16* __restrict__ W2b,
    const u16* __restrict__ ACT,  const u16* __restrict__ SGDb,
    u16* __restrict__ eo0, u16* __restrict__ eo1,
    float* __restrict__ sh0, float* __restrict__ sh1,
    const int* __restrict__ counts, const int* __restrict__ elist) {
  constexpr int KFULL = HDIM;            // row stride of A and B
  constexpr int KSTEP = 512 / 32;        // 16 steps over this half
  const int z = blockIdx.z;
  const int n0 = blockIdx.x * 128;
  const int m0 = blockIdx.y * 128;
  const bool routed = (z < 2 * NEXP);
  const int khalf = routed ? (z & 1) : (z - 2 * NEXP);
  const int koff = khalf * 512;

  int mlim; const u16* Ap; const u16* Bp; const int* lst = nullptr;
  if (routed) {
    const int e = z >> 1;
    mlim = counts[e];
    lst = elist + e * CAP;
    Ap = Hbuf;
    Bp = W2b + (size_t)e * DDIM * KFULL;
  } else {
    mlim = NTOK;
    Ap = ACT;
    Bp = SGDb;
  }
  if (m0 >= mlim) return;

  __shared__ __align__(16) u16 As[3 * BUFE];
  __shared__ __align__(16) u16 Bs[3 * BUFE];
  __shared__ int rowE[128];

  const int tid = threadIdx.x;
  const int wid = tid >> 6, lane = tid & 63;

  if (routed) {
    if (tid < 128) {
      int idx = m0 + tid; if (idx > mlim - 1) idx = mlim - 1;
      rowE[tid] = lst[idx];
    }
    __syncthreads();
  }

  const int row = tid >> 2;
  const int kcp = ((tid & 3) - ((row >> 1) & 3)) & 3;
  const int arow = routed ? rowE[row] : (m0 + row);
  const u16* aG = Ap + (size_t)arow * KFULL + koff + kcp * 8;
  const u16* bG = Bp + (size_t)(n0 + row) * KFULL + koff + kcp * 8;

  const int wm = (wid >> 2) * 64, wn = (wid & 3) * 32;
  const int lr = lane & 15, lk = lane >> 4;
  const int rslot = ((lk + ((lr >> 1) & 3)) & 3) * 8;

  const f32x4 zero = {0.f, 0.f, 0.f, 0.f};
  f32x4 acc[4][2];
#pragma unroll
  for (int i = 0; i < 4; ++i)
#pragma unroll
    for (int j = 0; j < 2; ++j) acc[i][j] = zero;

  auto STAGE = [&](int kt, int c) {
    gload16(aG + kt * 32, As + c * BUFE + tid * 8);
    gload16(bG + kt * 32, Bs + c * BUFE + tid * 8);
  };

  STAGE(0, 0); STAGE(1, 1);
  for (int kt = 0; kt < KSTEP; ++kt) {
    if (kt + 1 < KSTEP) asm volatile("s_waitcnt vmcnt(2)" ::: "memory");
    else                asm volatile("s_waitcnt vmcnt(0)" ::: "memory");
    __builtin_amdgcn_s_barrier();
    __builtin_amdgcn_sched_barrier(0);
    if (kt + 2 < KSTEP) STAGE(kt + 2, (kt + 2) % 3);
    const u16* ab = As + (kt % 3) * BUFE;
    const u16* bb = Bs + (kt % 3) * BUFE;
    short8 a[4], b[2];
#pragma unroll
    for (int i = 0; i < 4; ++i)
      a[i] = *(const short8*)&ab[(wm + i * 16 + lr) * 32 + rslot];
#pragma unroll
    for (int j = 0; j < 2; ++j)
      b[j] = *(const short8*)&bb[(wn + j * 16 + lr) * 32 + rslot];
    __builtin_amdgcn_s_setprio(1);
#pragma unroll
    for (int i = 0; i < 4; ++i)
#pragma unroll
      for (int j = 0; j < 2; ++j)
        acc[i][j] = __builtin_amdgcn_mfma_f32_16x16x32_bf16(a[i], b[j], acc[i][j], 0, 0, 0);
    __builtin_amdgcn_s_setprio(0);
  }

#pragma unroll
  for (int i = 0; i < 4; ++i) {
#pragma unroll
    for (int j = 0; j < 2; ++j) {
      const int col = n0 + wn + j * 16 + lr;
#pragma unroll
      for (int r = 0; r < 4; ++r) {
        const int m = wm + i * 16 + lk * 4 + r;
        if (routed) {
          if (m0 + m < mlim) {
            u16* dst = khalf ? eo1 : eo0;
            dst[(size_t)rowE[m] * DDIM + col] = f2bf(acc[i][j][r]);
          }
        } else {
          float* dst = khalf ? sh1 : sh0;
          dst[(size_t)(m0 + m) * DDIM + col] = acc[i][j][r];
        }
      }
    }
  }
}

// ------- combine: out = sh0+sh1 + w0*(eo0+eo1)[2t] + w1*(eo0+eo1)[2t+1] --------
__global__ __launch_bounds__(256) void combine_kernel(
    const u16* __restrict__ eo0, const u16* __restrict__ eo1,
    const float* __restrict__ sh0, const float* __restrict__ sh1,
    const float2* __restrict__ tW, float* __restrict__ out) {
  const int g = blockIdx.x * 256 + threadIdx.x;
  const int t = g >> 6;
  const int c0 = (g & 63) * 8;
  const float2 w = tW[t];
  const size_t r0 = (size_t)(t * 2) * DDIM + c0;
  const size_t r1 = (size_t)(t * 2 + 1) * DDIM + c0;
  const short8 a0 = *(const short8*)&eo0[r0];
  const short8 a1 = *(const short8*)&eo0[r1];
  const short8 b0 = *(const short8*)&eo1[r0];
  const short8 b1 = *(const short8*)&eo1[r1];
  const size_t so = (size_t)t * DDIM + c0;
  const float4 s0a = ((const float4*)(sh0 + so))[0];
  const float4 s0b = ((const float4*)(sh0 + so))[1];
  const float4 s1a = ((const float4*)(sh1 + so))[0];
  const float4 s1b = ((const float4*)(sh1 + so))[1];
  float o[8];
  o[0]=s0a.x+s1a.x; o[1]=s0a.y+s1a.y; o[2]=s0a.z+s1a.z; o[3]=s0a.w+s1a.w;
  o[4]=s0b.x+s1b.x; o[5]=s0b.y+s1b.y; o[6]=s0b.z+s1b.z; o[7]=s0b.w+s1b.w;
#pragma unroll
  for (int k = 0; k < 8; ++k)
    o[k] += w.x * (bf2f((u16)a0[k]) + bf2f((u16)b0[k])) +
            w.y * (bf2f((u16)a1[k]) + bf2f((u16)b1[k]));
  float4 v0 = {o[0], o[1], o[2], o[3]};
  float4 v1 = {o[4], o[5], o[6], o[7]};
  ((float4*)(out + so))[0] = v0;
  ((float4*)(out + so))[1] = v1;
}

extern "C" void kernel_launch(void* const* d_in, const int* in_sizes, int n_in,
                              void* d_out, int out_size, void* d_ws, size_t ws_size,
                              hipStream_t stream) {
  const float* x    = (const float*)d_in[0];
  const float* gw   = (const float*)d_in[1];
  const float* w1   = (const float*)d_in[2];
  const float* w2   = (const float*)d_in[3];
  const float* sgg  = (const float*)d_in[4];
  const float* sgu  = (const float*)d_in[5];
  const float* sgd  = (const float*)d_in[6];
  float* out = (float*)d_out;

  char* ws = (char*)d_ws;
  size_t off = 0;
  auto take = [&](size_t bytes) {
    size_t r = off; off += (bytes + 255) & ~(size_t)255; return r;
  };
  int*    counts = (int*)   (ws + take(NEXP * sizeof(int)));
  int*    elist  = (int*)   (ws + take((size_t)NEXP * CAP * sizeof(int)));
  int*    tIdx   = (int*)   (ws + take((size_t)NTOK * sizeof(int)));
  float2* tW     = (float2*)(ws + take((size_t)NTOK * sizeof(float2)));
  u16*    Xb     = (u16*)   (ws + take((size_t)NTOK * DDIM * 2));
  u16*    W1b    = (u16*)   (ws + take((size_t)NEXP * HDIM * DDIM * 2));
  u16*    W2b    = (u16*)   (ws + take((size_t)NEXP * DDIM * HDIM * 2));
  u16*    SGGb   = (u16*)   (ws + take((size_t)HDIM * DDIM * 2));
  u16*    SGUb   = (u16*)   (ws + take((size_t)HDIM * DDIM * 2));
  u16*    SGDb   = (u16*)   (ws + take((size_t)DDIM * HDIM * 2));
  u16*    Hbuf   = (u16*)   (ws + take((size_t)NTOK * 2 * HDIM * 2));
  u16*    ACT    = (u16*)   (ws + take((size_t)NTOK * HDIM * 2));
  u16*    eo0    = (u16*)   (ws + take((size_t)NTOK * 2 * DDIM * 2));
  u16*    eo1    = (u16*)   (ws + take((size_t)NTOK * 2 * DDIM * 2));
  float*  sh0    = (float*) (ws + take((size_t)NTOK * DDIM * 4));
  float*  sh1    = (float*) (ws + take((size_t)NTOK * DDIM * 4));
  if (off > ws_size) return;

  prep<<<dim3(3072), 256, 0, stream>>>(x, gw, w1, w2, sgg, sgu, sgd,
                                       Xb, W1b, W2b, SGGb, SGUb, SGDb, tIdx, tW);
  build_lists<<<NEXP, 256, 0, stream>>>(tIdx, counts, elist);
  // z<8: routed (x<8 of 128 cols); z=8: shared dual-B (x<16 of 64 cols)
  gemm_up<<<dim3(16, 32, NEXP + 1), 512, 0, stream>>>(
      Xb, W1b, SGGb, SGUb, Hbuf, ACT, counts, elist);
  gemm_down<<<dim3(DDIM / 128, 32, 2 * NEXP + 2), 512, 0, stream>>>(
      Hbuf, W2b, ACT, SGDb, eo0, eo1, sh0, sh1, counts, elist);
  combine_kernel<<<NTOK * 64 / 256, 256, 0, stream>>>(eo0, eo1, sh0, sh1, tW, out);
}

// Round 16
// 104.891 us; speedup vs baseline: 1.3143x; 1.0102x over previous
//
#include <hip/hip_runtime.h>
#include <hip/hip_bf16.h>

// MoE: B=2,S=2048,D=512,E=8,H=1024,TOP_K=2. fp32 in/out, bf16 MFMA internally.
// == r16: r11 core + W2/SGD conversion overlapped into gemm_up (z=0 slice) ==
// 5 launches: prep (router + X/W1/SGG/SGU cvt) -> build_lists
//   -> gemm_up   (z=0: W2+SGD fp32->bf16 converter slice, dispatches FIRST,
//                 overlaps the latency-bound GEMM which uses only 18% of HBM BW
//                 | z=1..8, x<8: routed silu->Hbuf
//                 | z=9, x<16: shared DUAL-B 64-col tiles, silu(g)*u -> ACT)
//   -> gemm_down (split-K=2: z<16 routed -> eo0/eo1 bf16; z=16/17 shared
//                 -> sh0/sh1 fp32; uniform 16 K-steps)
//   -> combine   (out = sh0+sh1 + w0*(eo0+eo1)[2t] + w1*(eo0+eo1)[2t+1]).
// GEMM core (r11, best measured): 128-row tile, BK=32, 8 waves, 3-buffer
// 1-barrier counted-vmcnt pipeline {vmcnt(2); s_barrier; sched_barrier(0);
// STAGE(kt+2); ds_read; [compiler counted lgkmcnt]; setprio(1); MFMA;
// setprio(0)}. T2 pre-swizzle (0 bank conflicts measured).
// Lessons encoded: occupancy > lookahead (r8/r9); no forced lgkmcnt(0) (r11);
// uniform block duration > traffic cuts (r14); XCD swizzle null (r6/r12);
// persistent strips regress (r13).

#define NTOK 4096
#define DDIM 512
#define HDIM 1024
#define NEXP 8
#define CAP  4096

typedef unsigned short u16;
typedef __attribute__((ext_vector_type(8))) short short8;
typedef __attribute__((ext_vector_type(4))) float f32x4;

__device__ __forceinline__ u16 f2bf(float f) {
  unsigned u = __float_as_uint(f);
  u += 0x7fffu + ((u >> 16) & 1u);   // RNE
  return (u16)(u >> 16);
}
__device__ __forceinline__ float bf2f(u16 v) {
  return __uint_as_float(((unsigned)v) << 16);
}
__device__ __forceinline__ float silu_f(float v) { return v / (1.0f + __expf(-v)); }

__device__ __forceinline__ void gload16(const u16* g, u16* l) {
  __builtin_amdgcn_global_load_lds((const __attribute__((address_space(1))) void*)g,
                                   (__attribute__((address_space(3))) void*)l, 16, 0, 0);
}

// ---------------- prep: router (blocks 0..1023) + W1/SGG/SGU cvt (rest) --------
__global__ __launch_bounds__(256) void prep(
    const float* __restrict__ x,   const float* __restrict__ gw,
    const float* __restrict__ w1,
    const float* __restrict__ sgg, const float* __restrict__ sgu,
    u16* __restrict__ Xb, u16* __restrict__ W1b,
    u16* __restrict__ SGGb, u16* __restrict__ SGUb,
    int* __restrict__ tIdx, float2* __restrict__ tW) {
  if (blockIdx.x < NTOK / 4) {
    const int lane = threadIdx.x & 63;
    const int wid  = threadIdx.x >> 6;
    const int t = blockIdx.x * 4 + wid;
    const float4* xr = (const float4*)(x + (size_t)t * DDIM + lane * 8);
    const float4 x0 = xr[0], x1 = xr[1];
    short8 xbv;
    xbv[0]=f2bf(x0.x); xbv[1]=f2bf(x0.y); xbv[2]=f2bf(x0.z); xbv[3]=f2bf(x0.w);
    xbv[4]=f2bf(x1.x); xbv[5]=f2bf(x1.y); xbv[6]=f2bf(x1.z); xbv[7]=f2bf(x1.w);
    *(short8*)&Xb[(size_t)t * DDIM + lane * 8] = xbv;
    float p[NEXP];
#pragma unroll
    for (int e = 0; e < NEXP; ++e) {
      const float4* gr = (const float4*)(gw + (size_t)e * DDIM + lane * 8);
      const float4 g0 = gr[0], g1 = gr[1];
      p[e] = x0.x*g0.x + x0.y*g0.y + x0.z*g0.z + x0.w*g0.w +
             x1.x*g1.x + x1.y*g1.y + x1.z*g1.z + x1.w*g1.w;
    }
#pragma unroll
    for (int e = 0; e < NEXP; ++e) {
#pragma unroll
      for (int m = 32; m >= 1; m >>= 1) p[e] += __shfl_xor(p[e], m);
    }
    if (lane == 0) {
      int i0 = 0; float v0 = p[0];
#pragma unroll
      for (int e = 1; e < NEXP; ++e) if (p[e] > v0) { v0 = p[e]; i0 = e; }
      int i1 = -1; float v1 = -3.0e38f;
#pragma unroll
      for (int e = 0; e < NEXP; ++e) if (e != i0 && p[e] > v1) { v1 = p[e]; i1 = e; }
      const float ex1 = __expf(v1 - v0);        // v0 >= v1
      const float inv = 1.0f / (1.0f + ex1);
      tIdx[t] = i0 | (i1 << 4);
      tW[t] = make_float2(inv, ex1 * inv);
    }
  } else {
    // weights needed by gemm_up only: [w1 | sgg | sgu]
    constexpr int NW1 = NEXP * HDIM * DDIM / 4;   // float4 count
    constexpr int NSG = HDIM * DDIM / 4;
    constexpr int TOT = NW1 + 2 * NSG;
    int i = (blockIdx.x - NTOK / 4) * 256 + threadIdx.x;
    const int stride = (gridDim.x - NTOK / 4) * 256;
    for (; i < TOT; i += stride) {
      const float* s; u16* d; int j = i;
      if (j < NW1)               { s = w1;  d = W1b;  }
      else if ((j -= NW1) < NSG) { s = sgg; d = SGGb; }
      else        { j -= NSG;      s = sgu; d = SGUb; }
      float4 v = ((const float4*)s)[j];
      ushort4 o;
      o.x = f2bf(v.x); o.y = f2bf(v.y); o.z = f2bf(v.z); o.w = f2bf(v.w);
      ((ushort4*)d)[j] = o;
    }
  }
}

// ---------------- per-expert list build (ballot + LDS counter) ------------------
__global__ __launch_bounds__(256) void build_lists(
    const int* __restrict__ tIdx,
    int* __restrict__ counts, int* __restrict__ elist) {
  const int e = blockIdx.x;
  __shared__ int cnt;
  if (threadIdx.x == 0) cnt = 0;
  __syncthreads();
  const int lane = threadIdx.x & 63;
  int* el = elist + e * CAP;
  for (int base = 0; base < NTOK; base += 256) {
    const int t = base + threadIdx.x;
    const int pk = tIdx[t];
#pragma unroll
    for (int slot = 0; slot < 2; ++slot) {
      const bool m = (((pk >> (slot * 4)) & 15) == e);
      const unsigned long long b = __ballot(m);
      const int my  = __popcll(b & ((1ull << lane) - 1));
      const int tot = __popcll(b);
      int wbase = 0;
      if (lane == 0 && tot) wbase = atomicAdd(&cnt, tot);
      wbase = __shfl(wbase, 0);
      if (m) el[wbase + my] = t * 2 + slot;
    }
  }
  __syncthreads();
  if (threadIdx.x == 0) counts[e] = cnt;
}

// ================= shared GEMM K-loop pieces ====================================
#define BUFE (128 * 32)   // elements per LDS buffer (128 rows x 32 bf16)

// ---------------- up GEMM: K=512, 8 waves ---------------------------------------
// z=0:          W2+SGD fp32->bf16 converter slice (512 blocks, dispatches first,
//               overlaps the latency-bound GEMM body; frees slots when done)
// z=1..8 (x<8): routed expert z-1, 128x128 tile, silu -> Hbuf[entry]
// z=9 (x<16):   shared dual-B, 128 rows x 64 cols; Bs = [SGG 64 | SGU 64];
//               epilogue: ACT = silu(gate)*up (fp32 accs).
__global__ __launch_bounds__(512, 6) void gemm_up(
    const u16* __restrict__ Xb, const u16* __restrict__ W1b,
    const u16* __restrict__ SGGb, const u16* __restrict__ SGUb,
    const float* __restrict__ w2f, const float* __restrict__ sgdf,
    u16* __restrict__ W2b, u16* __restrict__ SGDb,
    u16* __restrict__ Hbuf, u16* __restrict__ ACT,
    const int* __restrict__ counts, const int* __restrict__ elist) {
  constexpr int KDIM = DDIM, KSTEP = KDIM / 32;
  const int z = blockIdx.z;

  if (z == 0) {
    // ---- converter slice: W2 + SGD fp32 -> bf16, pure BW streaming ----
    constexpr int NW2 = NEXP * DDIM * HDIM / 4;   // float4 count
    constexpr int NSG = HDIM * DDIM / 4;
    constexpr int TOT = NW2 + NSG;
    const int cb = blockIdx.x + 16 * blockIdx.y;  // 0..511
    int i = cb * 512 + threadIdx.x;
    const int stride = 512 * 512;
    for (; i < TOT; i += stride) {
      const float* s; u16* d; int j = i;
      if (j < NW2) { s = w2f; d = W2b; }
      else         { j -= NW2; s = sgdf; d = SGDb; }
      float4 v = ((const float4*)s)[j];
      ushort4 o;
      o.x = f2bf(v.x); o.y = f2bf(v.y); o.z = f2bf(v.z); o.w = f2bf(v.w);
      ((ushort4*)d)[j] = o;
    }
    return;
  }

  const int m0 = blockIdx.y * 128;
  const bool routed = (z <= NEXP);

  int mlim; const u16* Bp = nullptr; const int* lst = nullptr;
  if (routed) {
    const int e = z - 1;
    if (blockIdx.x >= 8) return;         // routed uses 8 x-tiles of 128
    mlim = counts[e];
    lst = elist + e * CAP;
    Bp = W1b + (size_t)e * HDIM * KDIM;
  } else {
    mlim = NTOK;
  }
  if (m0 >= mlim) return;

  __shared__ __align__(16) u16 As[3 * BUFE];
  __shared__ __align__(16) u16 Bs[3 * BUFE];
  __shared__ int rowE[128];

  const int tid = threadIdx.x;
  const int wid = tid >> 6, lane = tid & 63;

  if (routed) {
    if (tid < 128) {
      int idx = m0 + tid; if (idx > mlim - 1) idx = mlim - 1;
      rowE[tid] = lst[idx];
    }
    __syncthreads();
  }

  // staging: one slot/thread. row=tid>>2, slotpos=tid&3; LDS dest linear;
  // global chunk pre-swizzled kc' = (slotpos - ((row>>1)&3))&3.
  const int row = tid >> 2;
  const int kcp = ((tid & 3) - ((row >> 1) & 3)) & 3;
  const int arow = routed ? (rowE[row] >> 1) : (m0 + row);
  const u16* aG = Xb + (size_t)arow * KDIM + kcp * 8;
  const u16* bG;
  if (routed) {
    bG = Bp + (size_t)(blockIdx.x * 128 + row) * KDIM + kcp * 8;
  } else {
    const int n0 = blockIdx.x * 64;
    bG = (row < 64) ? SGGb + (size_t)(n0 + row) * KDIM + kcp * 8
                    : SGUb + (size_t)(n0 + row - 64) * KDIM + kcp * 8;
  }

  const int lr = lane & 15, lk = lane >> 4;
  const int rslot = ((lk + ((lr >> 1) & 3)) & 3) * 8;   // swizzled read slot

  auto STAGE = [&](int kt, int c) {
    gload16(aG + kt * 32, As + c * BUFE + tid * 8);
    gload16(bG + kt * 32, Bs + c * BUFE + tid * 8);
  };

  const f32x4 zero = {0.f, 0.f, 0.f, 0.f};

  if (routed) {
    // ---- routed: wave tile 64x32, acc[4][2] ----
    const int n0 = blockIdx.x * 128;
    const int wm = (wid >> 2) * 64, wn = (wid & 3) * 32;
    f32x4 acc[4][2];
#pragma unroll
    for (int i = 0; i < 4; ++i)
#pragma unroll
      for (int j = 0; j < 2; ++j) acc[i][j] = zero;

    STAGE(0, 0); STAGE(1, 1);
    for (int kt = 0; kt < KSTEP; ++kt) {
      if (kt + 1 < KSTEP) asm volatile("s_waitcnt vmcnt(2)" ::: "memory");
      else                asm volatile("s_waitcnt vmcnt(0)" ::: "memory");
      __builtin_amdgcn_s_barrier();
      __builtin_amdgcn_sched_barrier(0);  // no read may hoist above the barrier
      if (kt + 2 < KSTEP) STAGE(kt + 2, (kt + 2) % 3);
      const u16* ab = As + (kt % 3) * BUFE;
      const u16* bb = Bs + (kt % 3) * BUFE;
      short8 a[4], b[2];
#pragma unroll
      for (int i = 0; i < 4; ++i)
        a[i] = *(const short8*)&ab[(wm + i * 16 + lr) * 32 + rslot];
#pragma unroll
      for (int j = 0; j < 2; ++j)
        b[j] = *(const short8*)&bb[(wn + j * 16 + lr) * 32 + rslot];
      // no forced lgkmcnt(0): compiler emits counted waits, MFMA overlaps reads
      __builtin_amdgcn_s_setprio(1);
#pragma unroll
      for (int i = 0; i < 4; ++i)
#pragma unroll
        for (int j = 0; j < 2; ++j)
          acc[i][j] = __builtin_amdgcn_mfma_f32_16x16x32_bf16(a[i], b[j], acc[i][j], 0, 0, 0);
      __builtin_amdgcn_s_setprio(0);
    }

    // epilogue: C/D layout col=lane&15, row=(lane>>4)*4+r  [m89-verified]
#pragma unroll
    for (int i = 0; i < 4; ++i) {
#pragma unroll
      for (int j = 0; j < 2; ++j) {
        const int col = n0 + wn + j * 16 + lr;
#pragma unroll
        for (int r = 0; r < 4; ++r) {
          const int m = wm + i * 16 + lk * 4 + r;
          if (m0 + m < mlim)
            Hbuf[(size_t)rowE[m] * HDIM + col] = f2bf(silu_f(acc[i][j][r]));
        }
      }
    }
  } else {
    // ---- shared dual-B: wave tile 64x16 (gate) + 64x16 (up) ----
    const int n0 = blockIdx.x * 64;
    const int wm = (wid >> 2) * 64, ws = (wid & 3) * 16;
    f32x4 ag[4], au[4];
#pragma unroll
    for (int i = 0; i < 4; ++i) { ag[i] = zero; au[i] = zero; }

    STAGE(0, 0); STAGE(1, 1);
    for (int kt = 0; kt < KSTEP; ++kt) {
      if (kt + 1 < KSTEP) asm volatile("s_waitcnt vmcnt(2)" ::: "memory");
      else                asm volatile("s_waitcnt vmcnt(0)" ::: "memory");
      __builtin_amdgcn_s_barrier();
      __builtin_amdgcn_sched_barrier(0);
      if (kt + 2 < KSTEP) STAGE(kt + 2, (kt + 2) % 3);
      const u16* ab = As + (kt % 3) * BUFE;
      const u16* bb = Bs + (kt % 3) * BUFE;
      short8 a[4], bg, bu;
#pragma unroll
      for (int i = 0; i < 4; ++i)
        a[i] = *(const short8*)&ab[(wm + i * 16 + lr) * 32 + rslot];
      bg = *(const short8*)&bb[(ws + lr) * 32 + rslot];        // SGG rows 0..63
      bu = *(const short8*)&bb[(64 + ws + lr) * 32 + rslot];   // SGU rows 64..127
      __builtin_amdgcn_s_setprio(1);
#pragma unroll
      for (int i = 0; i < 4; ++i) {
        ag[i] = __builtin_amdgcn_mfma_f32_16x16x32_bf16(a[i], bg, ag[i], 0, 0, 0);
        au[i] = __builtin_amdgcn_mfma_f32_16x16x32_bf16(a[i], bu, au[i], 0, 0, 0);
      }
      __builtin_amdgcn_s_setprio(0);
    }

#pragma unroll
    for (int i = 0; i < 4; ++i) {
      const int col = n0 + ws + lr;
#pragma unroll
      for (int r = 0; r < 4; ++r) {
        const int m = wm + i * 16 + lk * 4 + r;
        ACT[(size_t)(m0 + m) * HDIM + col] = f2bf(silu_f(ag[i][r]) * au[i][r]);
      }
    }
  }
}

// ---------------- down GEMM: split-K=2, 512 per half, N=512, 8 waves -----------
// z<16: routed, e=z>>1, khalf=z&1 -> (eo0|eo1)[entry] bf16
// z=16/17: shared khalf -> (sh0|sh1) fp32   (uniform 16 K-steps, no tail)
__global__ __launch_bounds__(512, 6) void gemm_down(
    const u16* __restrict__ Hbuf, const u16* __restrict__ W2b,
    const u16* __restrict__ ACT,  const u16* __restrict__ SGDb,
    u16* __restrict__ eo0, u16* __restrict__ eo1,
    float* __restrict__ sh0, float* __restrict__ sh1,
    const int* __restrict__ counts, const int* __restrict__ elist) {
  constexpr int KFULL = HDIM;            // row stride of A and B
  constexpr int KSTEP = 512 / 32;        // 16 steps over this half
  const int z = blockIdx.z;
  const int n0 = blockIdx.x * 128;
  const int m0 = blockIdx.y * 128;
  const bool routed = (z < 2 * NEXP);
  const int khalf = routed ? (z & 1) : (z - 2 * NEXP);
  const int koff = khalf * 512;

  int mlim; const u16* Ap; const u16* Bp; const int* lst = nullptr;
  if (routed) {
    const int e = z >> 1;
    mlim = counts[e];
    lst = elist + e * CAP;
    Ap = Hbuf;
    Bp = W2b + (size_t)e * DDIM * KFULL;
  } else {
    mlim = NTOK;
    Ap = ACT;
    Bp = SGDb;
  }
  if (m0 >= mlim) return;

  __shared__ __align__(16) u16 As[3 * BUFE];
  __shared__ __align__(16) u16 Bs[3 * BUFE];
  __shared__ int rowE[128];

  const int tid = threadIdx.x;
  const int wid = tid >> 6, lane = tid & 63;

  if (routed) {
    if (tid < 128) {
      int idx = m0 + tid; if (idx > mlim - 1) idx = mlim - 1;
      rowE[tid] = lst[idx];
    }
    __syncthreads();
  }

  const int row = tid >> 2;
  const int kcp = ((tid & 3) - ((row >> 1) & 3)) & 3;
  const int arow = routed ? rowE[row] : (m0 + row);
  const u16* aG = Ap + (size_t)arow * KFULL + koff + kcp * 8;
  const u16* bG = Bp + (size_t)(n0 + row) * KFULL + koff + kcp * 8;

  const int wm = (wid >> 2) * 64, wn = (wid & 3) * 32;
  const int lr = lane & 15, lk = lane >> 4;
  const int rslot = ((lk + ((lr >> 1) & 3)) & 3) * 8;

  const f32x4 zero = {0.f, 0.f, 0.f, 0.f};
  f32x4 acc[4][2];
#pragma unroll
  for (int i = 0; i < 4; ++i)
#pragma unroll
    for (int j = 0; j < 2; ++j) acc[i][j] = zero;

  auto STAGE = [&](int kt, int c) {
    gload16(aG + kt * 32, As + c * BUFE + tid * 8);
    gload16(bG + kt * 32, Bs + c * BUFE + tid * 8);
  };

  STAGE(0, 0); STAGE(1, 1);
  for (int kt = 0; kt < KSTEP; ++kt) {
    if (kt + 1 < KSTEP) asm volatile("s_waitcnt vmcnt(2)" ::: "memory");
    else                asm volatile("s_waitcnt vmcnt(0)" ::: "memory");
    __builtin_amdgcn_s_barrier();
    __builtin_amdgcn_sched_barrier(0);
    if (kt + 2 < KSTEP) STAGE(kt + 2, (kt + 2) % 3);
    const u16* ab = As + (kt % 3) * BUFE;
    const u16* bb = Bs + (kt % 3) * BUFE;
    short8 a[4], b[2];
#pragma unroll
    for (int i = 0; i < 4; ++i)
      a[i] = *(const short8*)&ab[(wm + i * 16 + lr) * 32 + rslot];
#pragma unroll
    for (int j = 0; j < 2; ++j)
      b[j] = *(const short8*)&bb[(wn + j * 16 + lr) * 32 + rslot];
    __builtin_amdgcn_s_setprio(1);
#pragma unroll
    for (int i = 0; i < 4; ++i)
#pragma unroll
      for (int j = 0; j < 2; ++j)
        acc[i][j] = __builtin_amdgcn_mfma_f32_16x16x32_bf16(a[i], b[j], acc[i][j], 0, 0, 0);
    __builtin_amdgcn_s_setprio(0);
  }

#pragma unroll
  for (int i = 0; i < 4; ++i) {
#pragma unroll
    for (int j = 0; j < 2; ++j) {
      const int col = n0 + wn + j * 16 + lr;
#pragma unroll
      for (int r = 0; r < 4; ++r) {
        const int m = wm + i * 16 + lk * 4 + r;
        if (routed) {
          if (m0 + m < mlim) {
            u16* dst = khalf ? eo1 : eo0;
            dst[(size_t)rowE[m] * DDIM + col] = f2bf(acc[i][j][r]);
          }
        } else {
          float* dst = khalf ? sh1 : sh0;
          dst[(size_t)(m0 + m) * DDIM + col] = acc[i][j][r];
        }
      }
    }
  }
}

// ------- combine: out = sh0+sh1 + w0*(eo0+eo1)[2t] + w1*(eo0+eo1)[2t+1] --------
__global__ __launch_bounds__(256) void combine_kernel(
    const u16* __restrict__ eo0, const u16* __restrict__ eo1,
    const float* __restrict__ sh0, const float* __restrict__ sh1,
    const float2* __restrict__ tW, float* __restrict__ out) {
  const int g = blockIdx.x * 256 + threadIdx.x;
  const int t = g >> 6;
  const int c0 = (g & 63) * 8;
  const float2 w = tW[t];
  const size_t r0 = (size_t)(t * 2) * DDIM + c0;
  const size_t r1 = (size_t)(t * 2 + 1) * DDIM + c0;
  const short8 a0 = *(const short8*)&eo0[r0];
  const short8 a1 = *(const short8*)&eo0[r1];
  const short8 b0 = *(const short8*)&eo1[r0];
  const short8 b1 = *(const short8*)&eo1[r1];
  const size_t so = (size_t)t * DDIM + c0;
  const float4 s0a = ((const float4*)(sh0 + so))[0];
  const float4 s0b = ((const float4*)(sh0 + so))[1];
  const float4 s1a = ((const float4*)(sh1 + so))[0];
  const float4 s1b = ((const float4*)(sh1 + so))[1];
  float o[8];
  o[0]=s0a.x+s1a.x; o[1]=s0a.y+s1a.y; o[2]=s0a.z+s1a.z; o[3]=s0a.w+s1a.w;
  o[4]=s0b.x+s1b.x; o[5]=s0b.y+s1b.y; o[6]=s0b.z+s1b.z; o[7]=s0b.w+s1b.w;
#pragma unroll
  for (int k = 0; k < 8; ++k)
    o[k] += w.x * (bf2f((u16)a0[k]) + bf2f((u16)b0[k])) +
            w.y * (bf2f((u16)a1[k]) + bf2f((u16)b1[k]));
  float4 v0 = {o[0], o[1], o[2], o[3]};
  float4 v1 = {o[4], o[5], o[6], o[7]};
  ((float4*)(out + so))[0] = v0;
  ((float4*)(out + so))[1] = v1;
}

extern "C" void kernel_launch(void* const* d_in, const int* in_sizes, int n_in,
                              void* d_out, int out_size, void* d_ws, size_t ws_size,
                              hipStream_t stream) {
  const float* x    = (const float*)d_in[0];
  const float* gw   = (const float*)d_in[1];
  const float* w1   = (const float*)d_in[2];
  const float* w2   = (const float*)d_in[3];
  const float* sgg  = (const float*)d_in[4];
  const float* sgu  = (const float*)d_in[5];
  const float* sgd  = (const float*)d_in[6];
  float* out = (float*)d_out;

  char* ws = (char*)d_ws;
  size_t off = 0;
  auto take = [&](size_t bytes) {
    size_t r = off; off += (bytes + 255) & ~(size_t)255; return r;
  };
  int*    counts = (int*)   (ws + take(NEXP * sizeof(int)));
  int*    elist  = (int*)   (ws + take((size_t)NEXP * CAP * sizeof(int)));
  int*    tIdx   = (int*)   (ws + take((size_t)NTOK * sizeof(int)));
  float2* tW     = (float2*)(ws + take((size_t)NTOK * sizeof(float2)));
  u16*    Xb     = (u16*)   (ws + take((size_t)NTOK * DDIM * 2));
  u16*    W1b    = (u16*)   (ws + take((size_t)NEXP * HDIM * DDIM * 2));
  u16*    W2b    = (u16*)   (ws + take((size_t)NEXP * DDIM * HDIM * 2));
  u16*    SGGb   = (u16*)   (ws + take((size_t)HDIM * DDIM * 2));
  u16*    SGUb   = (u16*)   (ws + take((size_t)HDIM * DDIM * 2));
  u16*    SGDb   = (u16*)   (ws + take((size_t)DDIM * HDIM * 2));
  u16*    Hbuf   = (u16*)   (ws + take((size_t)NTOK * 2 * HDIM * 2));
  u16*    ACT    = (u16*)   (ws + take((size_t)NTOK * HDIM * 2));
  u16*    eo0    = (u16*)   (ws + take((size_t)NTOK * 2 * DDIM * 2));
  u16*    eo1    = (u16*)   (ws + take((size_t)NTOK * 2 * DDIM * 2));
  float*  sh0    = (float*) (ws + take((size_t)NTOK * DDIM * 4));
  float*  sh1    = (float*) (ws + take((size_t)NTOK * DDIM * 4));
  if (off > ws_size) return;

  prep<<<dim3(3072), 256, 0, stream>>>(x, gw, w1, sgg, sgu,
                                       Xb, W1b, SGGb, SGUb, tIdx, tW);
  build_lists<<<NEXP, 256, 0, stream>>>(tIdx, counts, elist);
  // z=0: W2/SGD converter; z=1..8: routed (x<8); z=9: shared dual-B (x<16)
  gemm_up<<<dim3(16, 32, NEXP + 2), 512, 0, stream>>>(
      Xb, W1b, SGGb, SGUb, w2, sgd, W2b, SGDb, Hbuf, ACT, counts, elist);
  gemm_down<<<dim3(DDIM / 128, 32, 2 * NEXP + 2), 512, 0, stream>>>(
      Hbuf, W2b, ACT, SGDb, eo0, eo1, sh0, sh1, counts, elist);
  combine_kernel<<<NTOK * 64 / 256, 256, 0, stream>>>(eo0, eo1, sh0, sh1, tW, out);
}